// Round 15
// baseline (367.994 us; speedup 1.0000x reference)
//
#include <hip/hip_runtime.h>
#include <hip/hip_bf16.h>

#define B_ 2
#define L_ 2048
#define E_ 2048
#define H_ 16
#define D_ 128
#define M_ (B_*L_)
#define LOGIT_SCALE_MAX_ 4.6051701859880914f
#define LOG2E_ 1.44269504088896f

typedef __bf16 bf16_t;
typedef __bf16 bf16x2 __attribute__((ext_vector_type(2)));
typedef __bf16 bf16x4 __attribute__((ext_vector_type(4)));
typedef __bf16 bf16x8 __attribute__((ext_vector_type(8)));
typedef float f32x4 __attribute__((ext_vector_type(4)));
typedef float f32x16 __attribute__((ext_vector_type(16)));

// attn LDS: double-buffered K (64x128 @256B rows) + V^T (128x64 @128B rows), 32KB per buffer
#define KSB(p, r, cb) ((p) * 32768 + (r) * 256 + ((cb) ^ (((r) & 7) << 4)))
#define VSB(p, r, cb) ((p) * 32768 + 16384 + (r) * 128 + ((cb) ^ (((r) & 7) << 4)))

#define NW_ 4194304L   // E*E
#define NX_ 8388608L   // M*E

// ---------------- fused fp32 -> bf16 convert of all 7 inputs ----------------
__global__ void cvt_all_k(const float* __restrict__ xq, const float* __restrict__ xkv,
                          const float* __restrict__ bias,
                          const float* __restrict__ wq, const float* __restrict__ wk,
                          const float* __restrict__ wv, const float* __restrict__ wo,
                          bf16_t* __restrict__ ws) {
    const long NW4 = NW_ / 4, NX4 = NX_ / 4;
    long i4 = (long)blockIdx.x * 256 + threadIdx.x;
    const float* src; long off; float scale = 1.0f;
    if (i4 < 4 * NW4) {
        long r = i4 / NW4;
        src = (r == 0) ? wq : (r == 1) ? wk : (r == 2) ? wv : wo;
        off = i4 - r * NW4;
    } else if (i4 < 5 * NW4) {
        src = bias; off = i4 - 4 * NW4; scale = LOG2E_;
    } else if (i4 < 5 * NW4 + NX4) {
        src = xq; off = i4 - 5 * NW4;
    } else {
        src = xkv; off = i4 - 5 * NW4 - NX4;
    }
    float4 v = ((const float4*)src)[off];
    bf16x4 o = { (bf16_t)(v.x * scale), (bf16_t)(v.y * scale),
                 (bf16_t)(v.z * scale), (bf16_t)(v.w * scale) };
    ((bf16x4*)ws)[i4] = o;
}

// ---------------- mixed-tile 8-wave 4-phase NT GEMM (counted-vmcnt pipeline) ----------------
template<typename OutT, int GROUPS, int FULLB>
__global__ __launch_bounds__(512, 2) void gemm_mix(
    const bf16_t* __restrict__ A0g, const bf16_t* __restrict__ A1g,
    const bf16_t* __restrict__ W0, OutT* __restrict__ C0) {
    __shared__ __align__(16) unsigned char smem[131072];
    const int tid = threadIdx.x;
    const int wid = tid >> 6, lane = tid & 63;
    const int fr = lane & 15, fq = lane >> 4;
    const int wm = wid >> 2, wn = wid & 3;        // 2M x 4N wave grid
    int slot, hsel, isfull;
    {
        int bid = blockIdx.x;
        if (FULLB > 0 && bid < FULLB) {
            slot = (bid & 7) * (FULLB >> 3) + (bid >> 3);
            hsel = 0; isfull = 1;
        } else {
            const int n = (int)gridDim.x - FULLB;
            int sub = bid - FULLB;
            int s = (sub & 7) * (n >> 3) + (sub >> 3);
            slot = FULLB + (s >> 1); hsel = s & 1; isfull = 0;
        }
    }
    const int g = slot >> 7;
    const int r0 = slot & 127;
    const int bm = r0 >> 3, bn = r0 & 7;
    const long arow0 = (long)bm * 256 + (long)hsel * 128;
    const long brow0 = (long)bn * 256;
    const bf16_t* Ab = ((GROUPS > 1 && g > 0) ? A1g : A0g) + arow0 * E_;
    const bf16_t* Wb = W0 + (long)g * (long)E_ * E_ + brow0 * E_;
    const int srow = tid >> 2;
    const int sc16 = tid & 3;

    auto STG = [&](const bf16_t* base, unsigned matOff, int h, unsigned bufb, int kt) {
        #pragma unroll
        for (int kk = 0; kk < 2; ++kk) {
            int col = kk * 32 + ((sc16 ^ ((srow >> 1) & 3)) * 8);
            __builtin_amdgcn_global_load_lds(
                (const __attribute__((address_space(1))) void*)(base + (long)(h * 128 + srow) * E_ + kt + col),
                (__attribute__((address_space(3))) void*)(smem + bufb + matOff + h * 16384u + kk * 8192u + tid * 16), 16, 0, 0);
        }
    };
    auto LDA = [&](unsigned pb, int kk, int r) -> bf16x8 {
        int lr = r & 127;
        return *(const bf16x8*)(smem + pb + (unsigned)(r >> 7) * 16384u + kk * 8192u + lr * 64 + ((fq ^ ((lr >> 1) & 3)) << 4));
    };
    auto LDB = [&](unsigned pb, int kk, int ni) -> bf16x8 {
        int r = wn * 64 + ni * 16 + fr;
        int lr = r & 127;
        return *(const bf16x8*)(smem + pb + 32768u + (unsigned)(r >> 7) * 16384u + kk * 8192u + lr * 64 + ((fq ^ ((lr >> 1) & 3)) << 4));
    };

    if (FULLB > 0 && isfull) {
        f32x4 acc[8][4] = {};
        STG(Ab, 0u,     0, 0u, 0); STG(Ab, 0u,     1, 0u, 0);
        STG(Wb, 32768u, 0, 0u, 0); STG(Wb, 32768u, 1, 0u, 0);
        STG(Wb, 32768u, 0, 65536u, 64); STG(Wb, 32768u, 1, 65536u, 64);
        asm volatile("s_waitcnt vmcnt(4)" ::: "memory");
        __builtin_amdgcn_s_barrier();
        bf16x8 bq[2][4];
        #pragma unroll 2
        for (int t = 0; t < 32; ++t) {
            const unsigned pb = (unsigned)(t & 1) * 65536u;
            const unsigned sbA = 65536u - pb;
            const int ktA = ((t + 1) & 31) * 64;
            const int ktB = ((t + 2) & 31) * 64;
            bf16x8 a[2][2];
            #pragma unroll
            for (int kk = 0; kk < 2; ++kk) {
                a[kk][0] = LDA(pb, kk, wm * 128 + 0 * 16 + fr);
                a[kk][1] = LDA(pb, kk, wm * 128 + 1 * 16 + fr);
                #pragma unroll
                for (int ni = 0; ni < 4; ++ni) bq[kk][ni] = LDB(pb, kk, ni);
            }
            STG(Ab, 0u, 0, sbA, ktA);
            __builtin_amdgcn_s_barrier();
            asm volatile("s_waitcnt lgkmcnt(0)" ::: "memory");
            __builtin_amdgcn_sched_barrier(0);
            __builtin_amdgcn_s_setprio(1);
            #pragma unroll
            for (int kk = 0; kk < 2; ++kk)
                #pragma unroll
                for (int ni = 0; ni < 4; ++ni) {
                    acc[0][ni] = __builtin_amdgcn_mfma_f32_16x16x32_bf16(a[kk][0], bq[kk][ni], acc[0][ni], 0, 0, 0);
                    acc[1][ni] = __builtin_amdgcn_mfma_f32_16x16x32_bf16(a[kk][1], bq[kk][ni], acc[1][ni], 0, 0, 0);
                }
            __builtin_amdgcn_s_setprio(0);
            __builtin_amdgcn_s_barrier();
            #pragma unroll
            for (int kk = 0; kk < 2; ++kk) {
                a[kk][0] = LDA(pb, kk, wm * 128 + 2 * 16 + fr);
                a[kk][1] = LDA(pb, kk, wm * 128 + 3 * 16 + fr);
            }
            STG(Ab, 0u, 1, sbA, ktA);
            __builtin_amdgcn_s_barrier();
            asm volatile("s_waitcnt lgkmcnt(0)" ::: "memory");
            __builtin_amdgcn_sched_barrier(0);
            __builtin_amdgcn_s_setprio(1);
            #pragma unroll
            for (int kk = 0; kk < 2; ++kk)
                #pragma unroll
                for (int ni = 0; ni < 4; ++ni) {
                    acc[2][ni] = __builtin_amdgcn_mfma_f32_16x16x32_bf16(a[kk][0], bq[kk][ni], acc[2][ni], 0, 0, 0);
                    acc[3][ni] = __builtin_amdgcn_mfma_f32_16x16x32_bf16(a[kk][1], bq[kk][ni], acc[3][ni], 0, 0, 0);
                }
            __builtin_amdgcn_s_setprio(0);
            __builtin_amdgcn_s_barrier();
            #pragma unroll
            for (int kk = 0; kk < 2; ++kk) {
                a[kk][0] = LDA(pb, kk, wm * 128 + 4 * 16 + fr);
                a[kk][1] = LDA(pb, kk, wm * 128 + 5 * 16 + fr);
            }
            STG(Wb, 32768u, 0, pb, ktB);
            __builtin_amdgcn_s_barrier();
            asm volatile("s_waitcnt lgkmcnt(0)" ::: "memory");
            __builtin_amdgcn_sched_barrier(0);
            __builtin_amdgcn_s_setprio(1);
            #pragma unroll
            for (int kk = 0; kk < 2; ++kk)
                #pragma unroll
                for (int ni = 0; ni < 4; ++ni) {
                    acc[4][ni] = __builtin_amdgcn_mfma_f32_16x16x32_bf16(a[kk][0], bq[kk][ni], acc[4][ni], 0, 0, 0);
                    acc[5][ni] = __builtin_amdgcn_mfma_f32_16x16x32_bf16(a[kk][1], bq[kk][ni], acc[5][ni], 0, 0, 0);
                }
            __builtin_amdgcn_s_setprio(0);
            __builtin_amdgcn_s_barrier();
            #pragma unroll
            for (int kk = 0; kk < 2; ++kk) {
                a[kk][0] = LDA(pb, kk, wm * 128 + 6 * 16 + fr);
                a[kk][1] = LDA(pb, kk, wm * 128 + 7 * 16 + fr);
            }
            STG(Wb, 32768u, 1, pb, ktB);
            asm volatile("s_waitcnt vmcnt(4)" ::: "memory");
            __builtin_amdgcn_s_barrier();
            asm volatile("s_waitcnt lgkmcnt(0)" ::: "memory");
            __builtin_amdgcn_sched_barrier(0);
            __builtin_amdgcn_s_setprio(1);
            #pragma unroll
            for (int kk = 0; kk < 2; ++kk)
                #pragma unroll
                for (int ni = 0; ni < 4; ++ni) {
                    acc[6][ni] = __builtin_amdgcn_mfma_f32_16x16x32_bf16(a[kk][0], bq[kk][ni], acc[6][ni], 0, 0, 0);
                    acc[7][ni] = __builtin_amdgcn_mfma_f32_16x16x32_bf16(a[kk][1], bq[kk][ni], acc[7][ni], 0, 0, 0);
                }
            __builtin_amdgcn_s_setprio(0);
            __builtin_amdgcn_s_barrier();
        }
        asm volatile("s_waitcnt vmcnt(0)" ::: "memory");
        OutT* Cg = C0 + (long)g * M_ * E_;
        #pragma unroll
        for (int mi = 0; mi < 8; ++mi)
            #pragma unroll
            for (int i = 0; i < 4; ++i) {
                long row = arow0 + wm * 128 + mi * 16 + fq * 4 + i;
                OutT* crow = Cg + row * E_ + brow0 + wn * 64 + fr;
                #pragma unroll
                for (int ni = 0; ni < 4; ++ni)
                    crow[ni * 16] = (OutT)acc[mi][ni][i];
            }
    } else {
        f32x4 acc[4][4] = {};
        STG(Ab, 0u,     0, 0u, 0);
        STG(Wb, 32768u, 0, 0u, 0); STG(Wb, 32768u, 1, 0u, 0);
        STG(Wb, 32768u, 0, 65536u, 64); STG(Wb, 32768u, 1, 65536u, 64);
        asm volatile("s_waitcnt vmcnt(4)" ::: "memory");
        __builtin_amdgcn_s_barrier();
        bf16x8 bq[2][4];
        #pragma unroll 2
        for (int t = 0; t < 32; ++t) {
            const unsigned pb = (unsigned)(t & 1) * 65536u;
            const unsigned sbA = 65536u - pb;
            const int ktA = ((t + 1) & 31) * 64;
            const int ktB = ((t + 2) & 31) * 64;
            bf16x8 a[2];
            #pragma unroll
            for (int kk = 0; kk < 2; ++kk) {
                a[kk] = LDA(pb, kk, wm * 64 + 0 * 16 + fr);
                #pragma unroll
                for (int ni = 0; ni < 4; ++ni) bq[kk][ni] = LDB(pb, kk, ni);
            }
            STG(Ab, 0u, 0, sbA, ktA);
            __builtin_amdgcn_s_barrier();
            asm volatile("s_waitcnt lgkmcnt(0)" ::: "memory");
            __builtin_amdgcn_sched_barrier(0);
            __builtin_amdgcn_s_setprio(1);
            #pragma unroll
            for (int kk = 0; kk < 2; ++kk)
                #pragma unroll
                for (int ni = 0; ni < 4; ++ni)
                    acc[0][ni] = __builtin_amdgcn_mfma_f32_16x16x32_bf16(a[kk], bq[kk][ni], acc[0][ni], 0, 0, 0);
            __builtin_amdgcn_s_setprio(0);
            __builtin_amdgcn_s_barrier();
            #pragma unroll
            for (int kk = 0; kk < 2; ++kk) a[kk] = LDA(pb, kk, wm * 64 + 1 * 16 + fr);
            __builtin_amdgcn_s_barrier();
            asm volatile("s_waitcnt lgkmcnt(0)" ::: "memory");
            __builtin_amdgcn_sched_barrier(0);
            __builtin_amdgcn_s_setprio(1);
            #pragma unroll
            for (int kk = 0; kk < 2; ++kk)
                #pragma unroll
                for (int ni = 0; ni < 4; ++ni)
                    acc[1][ni] = __builtin_amdgcn_mfma_f32_16x16x32_bf16(a[kk], bq[kk][ni], acc[1][ni], 0, 0, 0);
            __builtin_amdgcn_s_setprio(0);
            __builtin_amdgcn_s_barrier();
            #pragma unroll
            for (int kk = 0; kk < 2; ++kk) a[kk] = LDA(pb, kk, wm * 64 + 2 * 16 + fr);
            STG(Wb, 32768u, 0, pb, ktB);
            __builtin_amdgcn_s_barrier();
            asm volatile("s_waitcnt lgkmcnt(0)" ::: "memory");
            __builtin_amdgcn_sched_barrier(0);
            __builtin_amdgcn_s_setprio(1);
            #pragma unroll
            for (int kk = 0; kk < 2; ++kk)
                #pragma unroll
                for (int ni = 0; ni < 4; ++ni)
                    acc[2][ni] = __builtin_amdgcn_mfma_f32_16x16x32_bf16(a[kk], bq[kk][ni], acc[2][ni], 0, 0, 0);
            __builtin_amdgcn_s_setprio(0);
            __builtin_amdgcn_s_barrier();
            #pragma unroll
            for (int kk = 0; kk < 2; ++kk) a[kk] = LDA(pb, kk, wm * 64 + 3 * 16 + fr);
            STG(Wb, 32768u, 1, pb, ktB);
            asm volatile("s_waitcnt vmcnt(4)" ::: "memory");
            __builtin_amdgcn_s_barrier();
            asm volatile("s_waitcnt lgkmcnt(0)" ::: "memory");
            __builtin_amdgcn_sched_barrier(0);
            __builtin_amdgcn_s_setprio(1);
            #pragma unroll
            for (int kk = 0; kk < 2; ++kk)
                #pragma unroll
                for (int ni = 0; ni < 4; ++ni)
                    acc[3][ni] = __builtin_amdgcn_mfma_f32_16x16x32_bf16(a[kk], bq[kk][ni], acc[3][ni], 0, 0, 0);
            __builtin_amdgcn_s_setprio(0);
            __builtin_amdgcn_s_barrier();
        }
        asm volatile("s_waitcnt vmcnt(0)" ::: "memory");
        OutT* Cg = C0 + (long)g * M_ * E_;
        #pragma unroll
        for (int mi = 0; mi < 4; ++mi)
            #pragma unroll
            for (int i = 0; i < 4; ++i) {
                long row = arow0 + wm * 64 + mi * 16 + fq * 4 + i;
                OutT* crow = Cg + row * E_ + brow0 + wn * 64 + fr;
                #pragma unroll
                for (int ni = 0; ni < 4; ++ni)
                    crow[ni * 16] = (OutT)acc[mi][ni][i];
            }
    }
}

// ---------------- merged: Q/K postprocess (blocks 0..32767) + V transpose (blocks 32768..34815) ----------------
__global__ __launch_bounds__(256) void post_tv_k(
    const bf16_t* __restrict__ Pq, const bf16_t* __restrict__ Pk,
    const bf16_t* __restrict__ Vp,
    const float* __restrict__ qsins, const float* __restrict__ ksins,
    const float* __restrict__ qnscale, const float* __restrict__ knscale,
    bf16_t* __restrict__ outq, bf16_t* __restrict__ outk, bf16_t* __restrict__ Vt) {
    __shared__ bf16_t t[64 * 64];
    if (blockIdx.x < 32768) {
        const int wid = threadIdx.x >> 6, lane = threadIdx.x & 63;
        const int half = blockIdx.x >> 14;
        const long g = (long)(blockIdx.x & 16383) * 4 + wid;
        const bf16_t* P = half ? Pk : Pq;
        const float* sins = half ? ksins : qsins;
        const float* nscale = half ? knscale : qnscale;
        bf16_t* out = half ? outk : outq;
        const int h = (int)(g % H_);
        const long bl = g / H_;
        const int b = (int)(bl / L_), l = (int)(bl % L_);
        bf16x2 xv = *(const bf16x2*)(P + g * D_ + lane * 2);
        float x0 = (float)xv[0], x1 = (float)xv[1];
        float ss = x0 * x0 + x1 * x1;
        #pragma unroll
        for (int m = 1; m < 64; m <<= 1) ss += __shfl_xor(ss, m);
        float r = rsqrtf(ss * (1.0f / 128.0f) + 1e-6f);
        float y0 = x0 * r * nscale[lane * 2];
        float y1 = x1 * r * nscale[lane * 2 + 1];
        float2 cs = *(const float2*)(sins + bl * D_ + lane * 2);
        float z0 = y0 * cs.x - y1 * cs.y;
        float z1 = y1 * cs.x + y0 * cs.y;
        float n2 = z0 * z0 + z1 * z1;
        #pragma unroll
        for (int m = 1; m < 64; m <<= 1) n2 += __shfl_xor(n2, m);
        float inv = 1.0f / fmaxf(sqrtf(n2), 1e-12f);
        bf16x2 o = { (bf16_t)(z0 * inv), (bf16_t)(z1 * inv) };
        *(bf16x2*)(out + (((long)b * H_ + h) * L_ + l) * D_ + lane * 2) = o;
    } else {
        const int idx = blockIdx.x - 32768;
        const int lb = idx & 31;
        const int db = (idx >> 5) & 1;
        const int bh = idx >> 6;
        const int b = bh >> 4, h = bh & 15;
        const bf16_t* src = Vp + ((long)(b * L_ + lb * 64) * H_ + h) * D_ + db * 64;
        #pragma unroll
        for (int it = 0; it < 2; ++it) {
            int i = it * 256 + threadIdx.x;
            int r = i >> 3, c8 = i & 7;
            bf16x8 v = *(const bf16x8*)(src + (long)r * H_ * D_ + c8 * 8);
            *(bf16x8*)&t[r * 64 + (c8 ^ (r >> 3)) * 8] = v;
        }
        __syncthreads();
        bf16_t* dst = Vt + ((long)(b * H_ + h) * D_ + db * 64) * L_ + lb * 64;
        #pragma unroll
        for (int it = 0; it < 2; ++it) {
            int i = it * 256 + threadIdx.x;
            int d = i >> 3, l8 = i & 7;
            bf16x8 o;
            #pragma unroll
            for (int j = 0; j < 8; ++j) {
                int l = l8 * 8 + j;
                o[j] = t[l * 64 + ((d >> 3) ^ l8) * 8 + (d & 7)];
            }
            *(bf16x8*)(dst + (long)d * L_ + l8 * 8) = o;
        }
    }
}

// ---------------- flash attention: 64 q/wave (2 col-blocks), gload_lds staging, QBLK=256 ----------------
// Each A-fragment (K / V^T) read feeds BOTH q-blocks: LDS reads per MFMA 1 -> 0.5.
__global__ __launch_bounds__(256, 1) void attn_k(
    const bf16_t* __restrict__ Qn, const bf16_t* __restrict__ Kn,
    const bf16_t* __restrict__ Vt, const bf16_t* __restrict__ biasb,
    const float* __restrict__ lsg, bf16_t* __restrict__ AO) {
    __shared__ __align__(16) unsigned char smem[65536];
    const int tid = threadIdx.x;
    const int w = tid >> 6, lane = tid & 63;
    const int lane31 = lane & 31, hi = lane >> 5;
    const int qb = blockIdx.x, bh = blockIdx.y;
    const int b = bh >> 4, h = bh & 15;
    const float lsc2 = __expf(fminf(lsg[h], LOGIT_SCALE_MAX_)) * LOG2E_;
    const int qr0 = qb * 256;
    const bf16_t* kbase = Kn + (((long)b * H_ + h) * L_) * D_;
    const bf16_t* vtbase = Vt + ((long)(b * H_ + h) * D_) * L_;

    // Q rows (2 col-blocks) in registers; bias row pointers
    bf16x8 qreg[2][8];
    const bf16_t* brow[2];
    #pragma unroll
    for (int q2 = 0; q2 < 2; ++q2) {
        const long qrow = (long)qr0 + w * 64 + q2 * 32 + lane31;
        const bf16_t* qp = Qn + (((long)b * H_ + h) * L_ + qrow) * D_;
        #pragma unroll
        for (int kk = 0; kk < 8; ++kk)
            qreg[q2][kk] = *(const bf16x8*)(qp + kk * 16 + 8 * hi);
        brow[q2] = biasb + qrow * L_;
    }

    f32x16 oacc[2][4] = {};
    float lsum[2] = {0.f, 0.f};

    // direct global->LDS staging with pre-swizzled source (rule-21-safe: same involution both sides)
    auto STAGE = [&](int p, int kt) {
        #pragma unroll
        for (int it = 0; it < 4; ++it) {
            int ci = it * 256 + tid;
            int kr = ci >> 4, kc = ci & 15;
            __builtin_amdgcn_global_load_lds(
                (const __attribute__((address_space(1))) void*)(kbase + (long)(kt + kr) * D_ + ((kc ^ (kr & 7)) * 8)),
                (__attribute__((address_space(3))) void*)(smem + p * 32768 + ci * 16), 16, 0, 0);
        }
        #pragma unroll
        for (int it = 0; it < 4; ++it) {
            int ci = it * 256 + tid;
            int vr = ci >> 3, vc = ci & 7;
            __builtin_amdgcn_global_load_lds(
                (const __attribute__((address_space(1))) void*)(vtbase + (long)vr * L_ + kt + ((vc ^ (vr & 7)) * 8)),
                (__attribute__((address_space(3))) void*)(smem + p * 32768 + 16384 + ci * 16), 16, 0, 0);
        }
    };

    STAGE(0, 0);
    asm volatile("s_waitcnt vmcnt(0)" ::: "memory");
    __builtin_amdgcn_s_barrier();
    int p = 0;

    for (int kt = 0; kt < L_; kt += 64) {
        // prefetch next tile into the other buffer (readers of p^1 finished before last barrier)
        if (kt + 64 < L_) STAGE(p ^ 1, kt + 64);
        bf16x4 bb[2][2][4];
        #pragma unroll
        for (int q2 = 0; q2 < 2; ++q2)
            #pragma unroll
            for (int f = 0; f < 2; ++f)
                #pragma unroll
                for (int rr = 0; rr < 4; ++rr)
                    bb[q2][f][rr] = *(const bf16x4*)(brow[q2] + kt + f * 32 + rr * 8 + 4 * hi);
        // QK: each ak read feeds both q-blocks
        f32x16 sacc[2][2] = {};
        __builtin_amdgcn_s_setprio(1);
        #pragma unroll
        for (int kk = 0; kk < 8; ++kk) {
            bf16x8 ak0 = *(const bf16x8*)(smem + KSB(p, lane31,      kk * 32 + 16 * hi));
            bf16x8 ak1 = *(const bf16x8*)(smem + KSB(p, 32 + lane31, kk * 32 + 16 * hi));
            sacc[0][0] = __builtin_amdgcn_mfma_f32_32x32x16_bf16(ak0, qreg[0][kk], sacc[0][0], 0, 0, 0);
            sacc[0][1] = __builtin_amdgcn_mfma_f32_32x32x16_bf16(ak1, qreg[0][kk], sacc[0][1], 0, 0, 0);
            sacc[1][0] = __builtin_amdgcn_mfma_f32_32x32x16_bf16(ak0, qreg[1][kk], sacc[1][0], 0, 0, 0);
            sacc[1][1] = __builtin_amdgcn_mfma_f32_32x32x16_bf16(ak1, qreg[1][kk], sacc[1][1], 0, 0, 0);
        }
        __builtin_amdgcn_s_setprio(0);
        // softmax per q-block (fixed m=0, base-2), build P^T B-fragments
        bf16x8 pb_[2][4];
        #pragma unroll
        for (int q2 = 0; q2 < 2; ++q2) {
            float ps = 0.f;
            unsigned int wv[2][4][2];
            #pragma unroll
            for (int f = 0; f < 2; ++f)
                #pragma unroll
                for (int rr = 0; rr < 4; ++rr)
                    #pragma unroll
                    for (int wi = 0; wi < 2; ++wi) {
                        float pa = __builtin_amdgcn_exp2f(sacc[q2][f][rr * 4 + wi * 2]     * lsc2 + (float)bb[q2][f][rr][wi * 2]);
                        float pc = __builtin_amdgcn_exp2f(sacc[q2][f][rr * 4 + wi * 2 + 1] * lsc2 + (float)bb[q2][f][rr][wi * 2 + 1]);
                        ps += pa + pc;
                        bf16x2 t2 = { (bf16_t)pa, (bf16_t)pc };
                        wv[f][rr][wi] = __builtin_bit_cast(unsigned int, t2);
                    }
            ps += __shfl_xor(ps, 32);
            lsum[q2] += ps;
            #pragma unroll
            for (int kk = 0; kk < 4; ++kk) {
                const int f = kk >> 1;
                const int a2 = (kk & 1) * 2;
                unsigned int A0 = wv[f][a2][0],     A1 = wv[f][a2][1];
                unsigned int B0 = wv[f][a2 + 1][0], B1 = wv[f][a2 + 1][1];
                unsigned int own0  = hi ? B0 : A0;
                unsigned int own1  = hi ? B1 : A1;
                unsigned int send0 = hi ? A0 : B0;
                unsigned int send1 = hi ? A1 : B1;
                unsigned int recv0 = __shfl_xor(send0, 32);
                unsigned int recv1 = __shfl_xor(send1, 32);
                uint4 uu;
                uu.x = hi ? recv0 : own0;
                uu.y = hi ? recv1 : own1;
                uu.z = hi ? own0  : recv0;
                uu.w = hi ? own1  : recv1;
                pb_[q2][kk] = __builtin_bit_cast(bf16x8, uu);
            }
        }
        // PV: each av read feeds both q-blocks
        __builtin_amdgcn_s_setprio(1);
        #pragma unroll
        for (int df = 0; df < 4; ++df)
            #pragma unroll
            for (int kk = 0; kk < 4; ++kk) {
                bf16x8 av = *(const bf16x8*)(smem + VSB(p, df * 32 + lane31, kk * 32 + 16 * hi));
                oacc[0][df] = __builtin_amdgcn_mfma_f32_32x32x16_bf16(av, pb_[0][kk], oacc[0][df], 0, 0, 0);
                oacc[1][df] = __builtin_amdgcn_mfma_f32_32x32x16_bf16(av, pb_[1][kk], oacc[1][df], 0, 0, 0);
            }
        __builtin_amdgcn_s_setprio(0);
        asm volatile("s_waitcnt vmcnt(0)" ::: "memory");
        __builtin_amdgcn_s_barrier();
        p ^= 1;
    }
    // epilogue: two passes (one per q-block) of LDS transpose + coalesced store
    #pragma unroll
    for (int q2 = 0; q2 < 2; ++q2) {
        float inv = 1.0f / lsum[q2];
        #pragma unroll
        for (int df = 0; df < 4; ++df)
            #pragma unroll
            for (int rg = 0; rg < 16; ++rg) {
                int d = df * 32 + (rg & 3) + 8 * (rg >> 2) + 4 * hi;
                *(bf16_t*)(smem + (w * 32 + lane31) * 264 + d * 2) = (bf16_t)(oacc[q2][df][rg] * inv);
            }
        __syncthreads();
        #pragma unroll
        for (int it = 0; it < 8; ++it) {
            int idx = it * 256 + tid;
            int row = idx >> 4, c = idx & 15;
            bf16x8 v = *(const bf16x8*)(smem + row * 264 + c * 16);
            long orow = (long)qr0 + (row >> 5) * 64 + q2 * 32 + (row & 31);
            *(bf16x8*)(AO + ((long)b * L_ + orow) * E_ + h * D_ + c * 8) = v;
        }
        __syncthreads();
    }
}

extern "C" void kernel_launch(void* const* d_in, const int* in_sizes, int n_in,
                              void* d_out, int out_size, void* d_ws, size_t ws_size,
                              hipStream_t stream) {
    const float* inputs_q  = (const float*)d_in[0];
    const float* inputs_kv = (const float*)d_in[1];
    const float* bias      = (const float*)d_in[2];
    const float* q_sin     = (const float*)d_in[3];
    const float* k_sin     = (const float*)d_in[4];
    const float* Wq        = (const float*)d_in[5];
    const float* Wk        = (const float*)d_in[6];
    const float* Wv        = (const float*)d_in[7];
    const float* Wo        = (const float*)d_in[8];
    const float* qns       = (const float*)d_in[9];
    const float* kns       = (const float*)d_in[10];
    const float* lsg       = (const float*)d_in[11];

    bf16_t* ws = (bf16_t*)d_ws;
    const long NW = NW_;
    const long NX = NX_;
    bf16_t* Wq_b   = ws;                    // Wq,Wk,Wv contiguous
    bf16_t* Wo_b   = ws + 3 * NW;
    bf16_t* bias_b = ws + 4 * NW;
    bf16_t* Xq     = bias_b + NW;
    bf16_t* Xkv    = Xq + NX;
    bf16_t* Qp     = Xkv + NX;              // Qp,Kp,Vp contiguous for grouped GEMM
    bf16_t* Kp     = Qp + NX;
    bf16_t* Vp     = Kp + NX;
    bf16_t* Qn = Xq;    // alias (Xq dead after GEMM Q)
    bf16_t* Kn = Xkv;   // alias (Xkv dead after GEMMs)
    bf16_t* AO = Qp;    // alias (Qp dead after postproc Q)
    bf16_t* Vtr = Kp;   // alias (Kp dead after postproc K)
    if (ws_size < (size_t)(5 * NW + 5 * NX) * 2) return;

    {
        long n4 = (5 * NW + 2 * NX) / 4;
        cvt_all_k<<<dim3((unsigned)(n4 / 256)), dim3(256), 0, stream>>>(
            inputs_q, inputs_kv, bias, Wq, Wk, Wv, Wo, ws);
    }

    // QKV projection: 256 full 256x256 blocks (Q,K) + 256 half 128x256 blocks (V)
    gemm_mix<bf16_t, 3, 256><<<dim3(512), dim3(512), 0, stream>>>(Xq, Xkv, Wq_b, Qp);

    post_tv_k<<<dim3(34816), dim3(256), 0, stream>>>(
        Qp, Kp, Vp, q_sin, k_sin, qns, kns, Qn, Kn, Vtr);

    attn_k<<<dim3(L_ / 256, B_ * H_), dim3(256), 0, stream>>>(Qn, Kn, Vtr, bias_b, lsg, AO);

    // O projection: 256 half 128x256 blocks = 1 clean round
    gemm_mix<float, 1, 0><<<dim3(256), dim3(512), 0, stream>>>(AO, AO, Wo_b, (float*)d_out);
}

// Round 16
// 321.687 us; speedup vs baseline: 1.1440x; 1.1440x over previous
//
#include <hip/hip_runtime.h>
#include <hip/hip_bf16.h>

#define B_ 2
#define L_ 2048
#define E_ 2048
#define H_ 16
#define D_ 128
#define M_ (B_*L_)
#define LOGIT_SCALE_MAX_ 4.6051701859880914f
#define LOG2E_ 1.44269504088896f

typedef __bf16 bf16_t;
typedef __bf16 bf16x2 __attribute__((ext_vector_type(2)));
typedef __bf16 bf16x4 __attribute__((ext_vector_type(4)));
typedef __bf16 bf16x8 __attribute__((ext_vector_type(8)));
typedef float f32x4 __attribute__((ext_vector_type(4)));
typedef float f32x16 __attribute__((ext_vector_type(16)));

// attn LDS: double-buffered K (64x128 @256B rows) + V^T (128x64 @128B rows), 32KB per buffer
#define KSB(p, r, cb) ((p) * 32768 + (r) * 256 + ((cb) ^ (((r) & 7) << 4)))
#define VSB(p, r, cb) ((p) * 32768 + 16384 + (r) * 128 + ((cb) ^ (((r) & 7) << 4)))

#define NW_ 4194304L   // E*E
#define NX_ 8388608L   // M*E

// ---------------- fused fp32 -> bf16 convert of all 7 inputs ----------------
__global__ void cvt_all_k(const float* __restrict__ xq, const float* __restrict__ xkv,
                          const float* __restrict__ bias,
                          const float* __restrict__ wq, const float* __restrict__ wk,
                          const float* __restrict__ wv, const float* __restrict__ wo,
                          bf16_t* __restrict__ ws) {
    const long NW4 = NW_ / 4, NX4 = NX_ / 4;
    long i4 = (long)blockIdx.x * 256 + threadIdx.x;
    const float* src; long off; float scale = 1.0f;
    if (i4 < 4 * NW4) {
        long r = i4 / NW4;
        src = (r == 0) ? wq : (r == 1) ? wk : (r == 2) ? wv : wo;
        off = i4 - r * NW4;
    } else if (i4 < 5 * NW4) {
        src = bias; off = i4 - 4 * NW4; scale = LOG2E_;
    } else if (i4 < 5 * NW4 + NX4) {
        src = xq; off = i4 - 5 * NW4;
    } else {
        src = xkv; off = i4 - 5 * NW4 - NX4;
    }
    float4 v = ((const float4*)src)[off];
    bf16x4 o = { (bf16_t)(v.x * scale), (bf16_t)(v.y * scale),
                 (bf16_t)(v.z * scale), (bf16_t)(v.w * scale) };
    ((bf16x4*)ws)[i4] = o;
}

// ---------------- mixed-tile 8-wave 4-phase NT GEMM (counted-vmcnt pipeline) ----------------
template<typename OutT, int GROUPS, int FULLB>
__global__ __launch_bounds__(512, 2) void gemm_mix(
    const bf16_t* __restrict__ A0g, const bf16_t* __restrict__ A1g,
    const bf16_t* __restrict__ W0, OutT* __restrict__ C0) {
    __shared__ __align__(16) unsigned char smem[131072];
    const int tid = threadIdx.x;
    const int wid = tid >> 6, lane = tid & 63;
    const int fr = lane & 15, fq = lane >> 4;
    const int wm = wid >> 2, wn = wid & 3;        // 2M x 4N wave grid
    int slot, hsel, isfull;
    {
        int bid = blockIdx.x;
        if (FULLB > 0 && bid < FULLB) {
            slot = (bid & 7) * (FULLB >> 3) + (bid >> 3);
            hsel = 0; isfull = 1;
        } else {
            const int n = (int)gridDim.x - FULLB;
            int sub = bid - FULLB;
            int s = (sub & 7) * (n >> 3) + (sub >> 3);
            slot = FULLB + (s >> 1); hsel = s & 1; isfull = 0;
        }
    }
    const int g = slot >> 7;
    const int r0 = slot & 127;
    const int bm = r0 >> 3, bn = r0 & 7;
    const long arow0 = (long)bm * 256 + (long)hsel * 128;
    const long brow0 = (long)bn * 256;
    const bf16_t* Ab = ((GROUPS > 1 && g > 0) ? A1g : A0g) + arow0 * E_;
    const bf16_t* Wb = W0 + (long)g * (long)E_ * E_ + brow0 * E_;
    const int srow = tid >> 2;
    const int sc16 = tid & 3;

    auto STG = [&](const bf16_t* base, unsigned matOff, int h, unsigned bufb, int kt) {
        #pragma unroll
        for (int kk = 0; kk < 2; ++kk) {
            int col = kk * 32 + ((sc16 ^ ((srow >> 1) & 3)) * 8);
            __builtin_amdgcn_global_load_lds(
                (const __attribute__((address_space(1))) void*)(base + (long)(h * 128 + srow) * E_ + kt + col),
                (__attribute__((address_space(3))) void*)(smem + bufb + matOff + h * 16384u + kk * 8192u + tid * 16), 16, 0, 0);
        }
    };
    auto LDA = [&](unsigned pb, int kk, int r) -> bf16x8 {
        int lr = r & 127;
        return *(const bf16x8*)(smem + pb + (unsigned)(r >> 7) * 16384u + kk * 8192u + lr * 64 + ((fq ^ ((lr >> 1) & 3)) << 4));
    };
    auto LDB = [&](unsigned pb, int kk, int ni) -> bf16x8 {
        int r = wn * 64 + ni * 16 + fr;
        int lr = r & 127;
        return *(const bf16x8*)(smem + pb + 32768u + (unsigned)(r >> 7) * 16384u + kk * 8192u + lr * 64 + ((fq ^ ((lr >> 1) & 3)) << 4));
    };

    if (FULLB > 0 && isfull) {
        f32x4 acc[8][4] = {};
        STG(Ab, 0u,     0, 0u, 0); STG(Ab, 0u,     1, 0u, 0);
        STG(Wb, 32768u, 0, 0u, 0); STG(Wb, 32768u, 1, 0u, 0);
        STG(Wb, 32768u, 0, 65536u, 64); STG(Wb, 32768u, 1, 65536u, 64);
        asm volatile("s_waitcnt vmcnt(4)" ::: "memory");
        __builtin_amdgcn_s_barrier();
        bf16x8 bq[2][4];
        #pragma unroll 2
        for (int t = 0; t < 32; ++t) {
            const unsigned pb = (unsigned)(t & 1) * 65536u;
            const unsigned sbA = 65536u - pb;
            const int ktA = ((t + 1) & 31) * 64;
            const int ktB = ((t + 2) & 31) * 64;
            bf16x8 a[2][2];
            #pragma unroll
            for (int kk = 0; kk < 2; ++kk) {
                a[kk][0] = LDA(pb, kk, wm * 128 + 0 * 16 + fr);
                a[kk][1] = LDA(pb, kk, wm * 128 + 1 * 16 + fr);
                #pragma unroll
                for (int ni = 0; ni < 4; ++ni) bq[kk][ni] = LDB(pb, kk, ni);
            }
            STG(Ab, 0u, 0, sbA, ktA);
            __builtin_amdgcn_s_barrier();
            asm volatile("s_waitcnt lgkmcnt(0)" ::: "memory");
            __builtin_amdgcn_sched_barrier(0);
            __builtin_amdgcn_s_setprio(1);
            #pragma unroll
            for (int kk = 0; kk < 2; ++kk)
                #pragma unroll
                for (int ni = 0; ni < 4; ++ni) {
                    acc[0][ni] = __builtin_amdgcn_mfma_f32_16x16x32_bf16(a[kk][0], bq[kk][ni], acc[0][ni], 0, 0, 0);
                    acc[1][ni] = __builtin_amdgcn_mfma_f32_16x16x32_bf16(a[kk][1], bq[kk][ni], acc[1][ni], 0, 0, 0);
                }
            __builtin_amdgcn_s_setprio(0);
            __builtin_amdgcn_s_barrier();
            #pragma unroll
            for (int kk = 0; kk < 2; ++kk) {
                a[kk][0] = LDA(pb, kk, wm * 128 + 2 * 16 + fr);
                a[kk][1] = LDA(pb, kk, wm * 128 + 3 * 16 + fr);
            }
            STG(Ab, 0u, 1, sbA, ktA);
            __builtin_amdgcn_s_barrier();
            asm volatile("s_waitcnt lgkmcnt(0)" ::: "memory");
            __builtin_amdgcn_sched_barrier(0);
            __builtin_amdgcn_s_setprio(1);
            #pragma unroll
            for (int kk = 0; kk < 2; ++kk)
                #pragma unroll
                for (int ni = 0; ni < 4; ++ni) {
                    acc[2][ni] = __builtin_amdgcn_mfma_f32_16x16x32_bf16(a[kk][0], bq[kk][ni], acc[2][ni], 0, 0, 0);
                    acc[3][ni] = __builtin_amdgcn_mfma_f32_16x16x32_bf16(a[kk][1], bq[kk][ni], acc[3][ni], 0, 0, 0);
                }
            __builtin_amdgcn_s_setprio(0);
            __builtin_amdgcn_s_barrier();
            #pragma unroll
            for (int kk = 0; kk < 2; ++kk) {
                a[kk][0] = LDA(pb, kk, wm * 128 + 4 * 16 + fr);
                a[kk][1] = LDA(pb, kk, wm * 128 + 5 * 16 + fr);
            }
            STG(Wb, 32768u, 0, pb, ktB);
            __builtin_amdgcn_s_barrier();
            asm volatile("s_waitcnt lgkmcnt(0)" ::: "memory");
            __builtin_amdgcn_sched_barrier(0);
            __builtin_amdgcn_s_setprio(1);
            #pragma unroll
            for (int kk = 0; kk < 2; ++kk)
                #pragma unroll
                for (int ni = 0; ni < 4; ++ni) {
                    acc[4][ni] = __builtin_amdgcn_mfma_f32_16x16x32_bf16(a[kk][0], bq[kk][ni], acc[4][ni], 0, 0, 0);
                    acc[5][ni] = __builtin_amdgcn_mfma_f32_16x16x32_bf16(a[kk][1], bq[kk][ni], acc[5][ni], 0, 0, 0);
                }
            __builtin_amdgcn_s_setprio(0);
            __builtin_amdgcn_s_barrier();
            #pragma unroll
            for (int kk = 0; kk < 2; ++kk) {
                a[kk][0] = LDA(pb, kk, wm * 128 + 6 * 16 + fr);
                a[kk][1] = LDA(pb, kk, wm * 128 + 7 * 16 + fr);
            }
            STG(Wb, 32768u, 1, pb, ktB);
            asm volatile("s_waitcnt vmcnt(4)" ::: "memory");
            __builtin_amdgcn_s_barrier();
            asm volatile("s_waitcnt lgkmcnt(0)" ::: "memory");
            __builtin_amdgcn_sched_barrier(0);
            __builtin_amdgcn_s_setprio(1);
            #pragma unroll
            for (int kk = 0; kk < 2; ++kk)
                #pragma unroll
                for (int ni = 0; ni < 4; ++ni) {
                    acc[6][ni] = __builtin_amdgcn_mfma_f32_16x16x32_bf16(a[kk][0], bq[kk][ni], acc[6][ni], 0, 0, 0);
                    acc[7][ni] = __builtin_amdgcn_mfma_f32_16x16x32_bf16(a[kk][1], bq[kk][ni], acc[7][ni], 0, 0, 0);
                }
            __builtin_amdgcn_s_setprio(0);
            __builtin_amdgcn_s_barrier();
        }
        asm volatile("s_waitcnt vmcnt(0)" ::: "memory");
        OutT* Cg = C0 + (long)g * M_ * E_;
        #pragma unroll
        for (int mi = 0; mi < 8; ++mi)
            #pragma unroll
            for (int i = 0; i < 4; ++i) {
                long row = arow0 + wm * 128 + mi * 16 + fq * 4 + i;
                OutT* crow = Cg + row * E_ + brow0 + wn * 64 + fr;
                #pragma unroll
                for (int ni = 0; ni < 4; ++ni)
                    crow[ni * 16] = (OutT)acc[mi][ni][i];
            }
    } else {
        f32x4 acc[4][4] = {};
        STG(Ab, 0u,     0, 0u, 0);
        STG(Wb, 32768u, 0, 0u, 0); STG(Wb, 32768u, 1, 0u, 0);
        STG(Wb, 32768u, 0, 65536u, 64); STG(Wb, 32768u, 1, 65536u, 64);
        asm volatile("s_waitcnt vmcnt(4)" ::: "memory");
        __builtin_amdgcn_s_barrier();
        bf16x8 bq[2][4];
        #pragma unroll 2
        for (int t = 0; t < 32; ++t) {
            const unsigned pb = (unsigned)(t & 1) * 65536u;
            const unsigned sbA = 65536u - pb;
            const int ktA = ((t + 1) & 31) * 64;
            const int ktB = ((t + 2) & 31) * 64;
            bf16x8 a[2];
            #pragma unroll
            for (int kk = 0; kk < 2; ++kk) {
                a[kk] = LDA(pb, kk, wm * 64 + 0 * 16 + fr);
                #pragma unroll
                for (int ni = 0; ni < 4; ++ni) bq[kk][ni] = LDB(pb, kk, ni);
            }
            STG(Ab, 0u, 0, sbA, ktA);
            __builtin_amdgcn_s_barrier();
            asm volatile("s_waitcnt lgkmcnt(0)" ::: "memory");
            __builtin_amdgcn_sched_barrier(0);
            __builtin_amdgcn_s_setprio(1);
            #pragma unroll
            for (int kk = 0; kk < 2; ++kk)
                #pragma unroll
                for (int ni = 0; ni < 4; ++ni)
                    acc[0][ni] = __builtin_amdgcn_mfma_f32_16x16x32_bf16(a[kk], bq[kk][ni], acc[0][ni], 0, 0, 0);
            __builtin_amdgcn_s_setprio(0);
            __builtin_amdgcn_s_barrier();
            #pragma unroll
            for (int kk = 0; kk < 2; ++kk) a[kk] = LDA(pb, kk, wm * 64 + 1 * 16 + fr);
            __builtin_amdgcn_s_barrier();
            asm volatile("s_waitcnt lgkmcnt(0)" ::: "memory");
            __builtin_amdgcn_sched_barrier(0);
            __builtin_amdgcn_s_setprio(1);
            #pragma unroll
            for (int kk = 0; kk < 2; ++kk)
                #pragma unroll
                for (int ni = 0; ni < 4; ++ni)
                    acc[1][ni] = __builtin_amdgcn_mfma_f32_16x16x32_bf16(a[kk], bq[kk][ni], acc[1][ni], 0, 0, 0);
            __builtin_amdgcn_s_setprio(0);
            __builtin_amdgcn_s_barrier();
            #pragma unroll
            for (int kk = 0; kk < 2; ++kk) a[kk] = LDA(pb, kk, wm * 64 + 2 * 16 + fr);
            STG(Wb, 32768u, 0, pb, ktB);
            __builtin_amdgcn_s_barrier();
            asm volatile("s_waitcnt lgkmcnt(0)" ::: "memory");
            __builtin_amdgcn_sched_barrier(0);
            __builtin_amdgcn_s_setprio(1);
            #pragma unroll
            for (int kk = 0; kk < 2; ++kk)
                #pragma unroll
                for (int ni = 0; ni < 4; ++ni)
                    acc[2][ni] = __builtin_amdgcn_mfma_f32_16x16x32_bf16(a[kk], bq[kk][ni], acc[2][ni], 0, 0, 0);
            __builtin_amdgcn_s_setprio(0);
            __builtin_amdgcn_s_barrier();
            #pragma unroll
            for (int kk = 0; kk < 2; ++kk) a[kk] = LDA(pb, kk, wm * 64 + 3 * 16 + fr);
            STG(Wb, 32768u, 1, pb, ktB);
            asm volatile("s_waitcnt vmcnt(4)" ::: "memory");
            __builtin_amdgcn_s_barrier();
            asm volatile("s_waitcnt lgkmcnt(0)" ::: "memory");
            __builtin_amdgcn_sched_barrier(0);
            __builtin_amdgcn_s_setprio(1);
            #pragma unroll
            for (int kk = 0; kk < 2; ++kk)
                #pragma unroll
                for (int ni = 0; ni < 4; ++ni)
                    acc[3][ni] = __builtin_amdgcn_mfma_f32_16x16x32_bf16(a[kk], bq[kk][ni], acc[3][ni], 0, 0, 0);
            __builtin_amdgcn_s_setprio(0);
            __builtin_amdgcn_s_barrier();
        }
        asm volatile("s_waitcnt vmcnt(0)" ::: "memory");
        OutT* Cg = C0 + (long)g * M_ * E_;
        #pragma unroll
        for (int mi = 0; mi < 4; ++mi)
            #pragma unroll
            for (int i = 0; i < 4; ++i) {
                long row = arow0 + wm * 64 + mi * 16 + fq * 4 + i;
                OutT* crow = Cg + row * E_ + brow0 + wn * 64 + fr;
                #pragma unroll
                for (int ni = 0; ni < 4; ++ni)
                    crow[ni * 16] = (OutT)acc[mi][ni][i];
            }
    }
}

// ---------------- merged: Q/K postprocess (blocks 0..32767) + V transpose (blocks 32768..34815) ----------------
__global__ __launch_bounds__(256) void post_tv_k(
    const bf16_t* __restrict__ Pq, const bf16_t* __restrict__ Pk,
    const bf16_t* __restrict__ Vp,
    const float* __restrict__ qsins, const float* __restrict__ ksins,
    const float* __restrict__ qnscale, const float* __restrict__ knscale,
    bf16_t* __restrict__ outq, bf16_t* __restrict__ outk, bf16_t* __restrict__ Vt) {
    __shared__ bf16_t t[64 * 64];
    if (blockIdx.x < 32768) {
        const int wid = threadIdx.x >> 6, lane = threadIdx.x & 63;
        const int half = blockIdx.x >> 14;
        const long g = (long)(blockIdx.x & 16383) * 4 + wid;
        const bf16_t* P = half ? Pk : Pq;
        const float* sins = half ? ksins : qsins;
        const float* nscale = half ? knscale : qnscale;
        bf16_t* out = half ? outk : outq;
        const int h = (int)(g % H_);
        const long bl = g / H_;
        const int b = (int)(bl / L_), l = (int)(bl % L_);
        bf16x2 xv = *(const bf16x2*)(P + g * D_ + lane * 2);
        float x0 = (float)xv[0], x1 = (float)xv[1];
        float ss = x0 * x0 + x1 * x1;
        #pragma unroll
        for (int m = 1; m < 64; m <<= 1) ss += __shfl_xor(ss, m);
        float r = rsqrtf(ss * (1.0f / 128.0f) + 1e-6f);
        float y0 = x0 * r * nscale[lane * 2];
        float y1 = x1 * r * nscale[lane * 2 + 1];
        float2 cs = *(const float2*)(sins + bl * D_ + lane * 2);
        float z0 = y0 * cs.x - y1 * cs.y;
        float z1 = y1 * cs.x + y0 * cs.y;
        float n2 = z0 * z0 + z1 * z1;
        #pragma unroll
        for (int m = 1; m < 64; m <<= 1) n2 += __shfl_xor(n2, m);
        float inv = 1.0f / fmaxf(sqrtf(n2), 1e-12f);
        bf16x2 o = { (bf16_t)(z0 * inv), (bf16_t)(z1 * inv) };
        *(bf16x2*)(out + (((long)b * H_ + h) * L_ + l) * D_ + lane * 2) = o;
    } else {
        const int idx = blockIdx.x - 32768;
        const int lb = idx & 31;
        const int db = (idx >> 5) & 1;
        const int bh = idx >> 6;
        const int b = bh >> 4, h = bh & 15;
        const bf16_t* src = Vp + ((long)(b * L_ + lb * 64) * H_ + h) * D_ + db * 64;
        #pragma unroll
        for (int it = 0; it < 2; ++it) {
            int i = it * 256 + threadIdx.x;
            int r = i >> 3, c8 = i & 7;
            bf16x8 v = *(const bf16x8*)(src + (long)r * H_ * D_ + c8 * 8);
            *(bf16x8*)&t[r * 64 + (c8 ^ (r >> 3)) * 8] = v;
        }
        __syncthreads();
        bf16_t* dst = Vt + ((long)(b * H_ + h) * D_ + db * 64) * L_ + lb * 64;
        #pragma unroll
        for (int it = 0; it < 2; ++it) {
            int i = it * 256 + threadIdx.x;
            int d = i >> 3, l8 = i & 7;
            bf16x8 o;
            #pragma unroll
            for (int j = 0; j < 8; ++j) {
                int l = l8 * 8 + j;
                o[j] = t[l * 64 + ((d >> 3) ^ l8) * 8 + (d & 7)];
            }
            *(bf16x8*)(dst + (long)d * L_ + l8 * 8) = o;
        }
    }
}

// ---------------- flash attention (32x32 swapped, no-max softmax, 1 barrier/tile) ----------------
__global__ __launch_bounds__(256, 2) void attn_k(
    const bf16_t* __restrict__ Qn, const bf16_t* __restrict__ Kn,
    const bf16_t* __restrict__ Vt, const bf16_t* __restrict__ biasb,
    const float* __restrict__ lsg, bf16_t* __restrict__ AO) {
    __shared__ __align__(16) unsigned char smem[65536];
    const int tid = threadIdx.x;
    const int w = tid >> 6, lane = tid & 63;
    const int lane31 = lane & 31, hi = lane >> 5;
    const int qb = blockIdx.x, bh = blockIdx.y;
    const int b = bh >> 4, h = bh & 15;
    const float lsc2 = __expf(fminf(lsg[h], LOGIT_SCALE_MAX_)) * LOG2E_;
    const int qr0 = qb * 128;
    const int qloc = w * 32 + lane31;
    const bf16_t* qrow  = Qn + (((long)b * H_ + h) * L_ + qr0 + qloc) * D_;
    const bf16_t* kbase = Kn + (((long)b * H_ + h) * L_) * D_;
    const bf16_t* vtbase = Vt + ((long)(b * H_ + h) * D_) * L_;
    const bf16_t* brow  = biasb + (long)(qr0 + qloc) * L_;

    const int ksr = tid >> 4, ksc = (tid & 15) * 8;
    const int vsr = tid >> 3, vsc = (tid & 7) * 8;

    bf16x8 qreg[8];
    #pragma unroll
    for (int kk = 0; kk < 8; ++kk)
        qreg[kk] = *(const bf16x8*)(qrow + kk * 16 + 8 * hi);

    f32x16 oacc[4] = {};
    float l_ = 0.f;

    bf16x8 kreg[4], vreg[4];
    #pragma unroll
    for (int it = 0; it < 4; ++it) {
        kreg[it] = *(const bf16x8*)(kbase + (long)(it * 16 + ksr) * D_ + ksc);
        vreg[it] = *(const bf16x8*)(vtbase + (long)(it * 32 + vsr) * L_ + vsc);
    }
    #pragma unroll
    for (int it = 0; it < 4; ++it) {
        *(bf16x8*)(smem + KSB(0, it * 16 + ksr, ksc * 2)) = kreg[it];
        *(bf16x8*)(smem + VSB(0, it * 32 + vsr, vsc * 2)) = vreg[it];
    }
    int p = 0;

    for (int kt = 0; kt < L_; kt += 64) {
        __syncthreads();
        const int ktn = (kt + 64 < L_) ? kt + 64 : 0;
        #pragma unroll
        for (int it = 0; it < 4; ++it) {
            kreg[it] = *(const bf16x8*)(kbase + (long)(ktn + it * 16 + ksr) * D_ + ksc);
            vreg[it] = *(const bf16x8*)(vtbase + (long)(it * 32 + vsr) * L_ + ktn + vsc);
        }
        bf16x4 bb[2][4];
        #pragma unroll
        for (int f = 0; f < 2; ++f)
            #pragma unroll
            for (int rr = 0; rr < 4; ++rr)
                bb[f][rr] = *(const bf16x4*)(brow + kt + f * 32 + rr * 8 + 4 * hi);
        f32x16 sacc[2] = {};
        __builtin_amdgcn_s_setprio(1);
        #pragma unroll
        for (int kk = 0; kk < 8; ++kk) {
            bf16x8 ak0 = *(const bf16x8*)(smem + KSB(p, lane31,      kk * 32 + 16 * hi));
            bf16x8 ak1 = *(const bf16x8*)(smem + KSB(p, 32 + lane31, kk * 32 + 16 * hi));
            sacc[0] = __builtin_amdgcn_mfma_f32_32x32x16_bf16(ak0, qreg[kk], sacc[0], 0, 0, 0);
            sacc[1] = __builtin_amdgcn_mfma_f32_32x32x16_bf16(ak1, qreg[kk], sacc[1], 0, 0, 0);
        }
        __builtin_amdgcn_s_setprio(0);
        float ps = 0.f;
        unsigned int wv[2][4][2];
        #pragma unroll
        for (int f = 0; f < 2; ++f)
            #pragma unroll
            for (int rr = 0; rr < 4; ++rr)
                #pragma unroll
                for (int wi = 0; wi < 2; ++wi) {
                    float pa = __builtin_amdgcn_exp2f(sacc[f][rr * 4 + wi * 2]     * lsc2 + (float)bb[f][rr][wi * 2]);
                    float pc = __builtin_amdgcn_exp2f(sacc[f][rr * 4 + wi * 2 + 1] * lsc2 + (float)bb[f][rr][wi * 2 + 1]);
                    ps += pa + pc;
                    bf16x2 t = { (bf16_t)pa, (bf16_t)pc };
                    wv[f][rr][wi] = __builtin_bit_cast(unsigned int, t);
                }
        ps += __shfl_xor(ps, 32);
        l_ += ps;
        bf16x8 pb_[4];
        #pragma unroll
        for (int kk = 0; kk < 4; ++kk) {
            const int f = kk >> 1;
            const int a2 = (kk & 1) * 2;
            unsigned int A0 = wv[f][a2][0],     A1 = wv[f][a2][1];
            unsigned int B0 = wv[f][a2 + 1][0], B1 = wv[f][a2 + 1][1];
            unsigned int own0  = hi ? B0 : A0;
            unsigned int own1  = hi ? B1 : A1;
            unsigned int send0 = hi ? A0 : B0;
            unsigned int send1 = hi ? A1 : B1;
            unsigned int recv0 = __shfl_xor(send0, 32);
            unsigned int recv1 = __shfl_xor(send1, 32);
            uint4 uu;
            uu.x = hi ? recv0 : own0;
            uu.y = hi ? recv1 : own1;
            uu.z = hi ? own0  : recv0;
            uu.w = hi ? own1  : recv1;
            pb_[kk] = __builtin_bit_cast(bf16x8, uu);
        }
        __builtin_amdgcn_s_setprio(1);
        #pragma unroll
        for (int df = 0; df < 4; ++df)
            #pragma unroll
            for (int kk = 0; kk < 4; ++kk) {
                bf16x8 av = *(const bf16x8*)(smem + VSB(p, df * 32 + lane31, kk * 32 + 16 * hi));
                oacc[df] = __builtin_amdgcn_mfma_f32_32x32x16_bf16(av, pb_[kk], oacc[df], 0, 0, 0);
            }
        __builtin_amdgcn_s_setprio(0);
        if (kt + 64 < L_) {
            #pragma unroll
            for (int it = 0; it < 4; ++it) {
                *(bf16x8*)(smem + KSB(p ^ 1, it * 16 + ksr, ksc * 2)) = kreg[it];
                *(bf16x8*)(smem + VSB(p ^ 1, it * 32 + vsr, vsc * 2)) = vreg[it];
            }
        }
        p ^= 1;
    }
    __syncthreads();
    float inv = 1.0f / l_;
    #pragma unroll
    for (int df = 0; df < 4; ++df)
        #pragma unroll
        for (int rg = 0; rg < 16; ++rg) {
            int d = df * 32 + (rg & 3) + 8 * (rg >> 2) + 4 * hi;
            *(bf16_t*)(smem + qloc * 264 + d * 2) = (bf16_t)(oacc[df][rg] * inv);
        }
    __syncthreads();
    #pragma unroll
    for (int it = 0; it < 8; ++it) {
        int idx = it * 256 + tid;
        int row = idx >> 4, c = idx & 15;
        bf16x8 v = *(const bf16x8*)(smem + row * 264 + c * 16);
        *(bf16x8*)(AO + ((long)b * L_ + qr0 + row) * E_ + h * D_ + c * 8) = v;
    }
}

extern "C" void kernel_launch(void* const* d_in, const int* in_sizes, int n_in,
                              void* d_out, int out_size, void* d_ws, size_t ws_size,
                              hipStream_t stream) {
    const float* inputs_q  = (const float*)d_in[0];
    const float* inputs_kv = (const float*)d_in[1];
    const float* bias      = (const float*)d_in[2];
    const float* q_sin     = (const float*)d_in[3];
    const float* k_sin     = (const float*)d_in[4];
    const float* Wq        = (const float*)d_in[5];
    const float* Wk        = (const float*)d_in[6];
    const float* Wv        = (const float*)d_in[7];
    const float* Wo        = (const float*)d_in[8];
    const float* qns       = (const float*)d_in[9];
    const float* kns       = (const float*)d_in[10];
    const float* lsg       = (const float*)d_in[11];

    bf16_t* ws = (bf16_t*)d_ws;
    const long NW = NW_;
    const long NX = NX_;
    bf16_t* Wq_b   = ws;                    // Wq,Wk,Wv contiguous
    bf16_t* Wo_b   = ws + 3 * NW;
    bf16_t* bias_b = ws + 4 * NW;
    bf16_t* Xq     = bias_b + NW;
    bf16_t* Xkv    = Xq + NX;
    bf16_t* Qp     = Xkv + NX;              // Qp,Kp,Vp contiguous for grouped GEMM
    bf16_t* Kp     = Qp + NX;
    bf16_t* Vp     = Kp + NX;
    bf16_t* Qn = Xq;    // alias (Xq dead after GEMM Q)
    bf16_t* Kn = Xkv;   // alias (Xkv dead after GEMMs)
    bf16_t* AO = Qp;    // alias (Qp dead after postproc Q)
    bf16_t* Vtr = Kp;   // alias (Kp dead after postproc K)
    if (ws_size < (size_t)(5 * NW + 5 * NX) * 2) return;

    {
        long n4 = (5 * NW + 2 * NX) / 4;
        cvt_all_k<<<dim3((unsigned)(n4 / 256)), dim3(256), 0, stream>>>(
            inputs_q, inputs_kv, bias, Wq, Wk, Wv, Wo, ws);
    }

    // QKV projection: 256 full 256x256 blocks (Q,K) + 256 half 128x256 blocks (V) = 2 clean rounds
    gemm_mix<bf16_t, 3, 256><<<dim3(512), dim3(512), 0, stream>>>(Xq, Xkv, Wq_b, Qp);

    post_tv_k<<<dim3(34816), dim3(256), 0, stream>>>(
        Qp, Kp, Vp, q_sin, k_sin, qns, kns, Qn, Kn, Vtr);

    attn_k<<<dim3(L_ / 128, B_ * H_), dim3(256), 0, stream>>>(Qn, Kn, Vtr, bias_b, lsg, AO);

    // O projection: 256 half 128x256 blocks = 1 clean round
    gemm_mix<float, 1, 0><<<dim3(256), dim3(512), 0, stream>>>(AO, AO, Wo_b, (float*)d_out);
}

// Round 17
// 309.123 us; speedup vs baseline: 1.1904x; 1.0406x over previous
//
#include <hip/hip_runtime.h>
#include <hip/hip_bf16.h>

#define B_ 2
#define L_ 2048
#define E_ 2048
#define H_ 16
#define D_ 128
#define M_ (B_*L_)
#define LOGIT_SCALE_MAX_ 4.6051701859880914f
#define LOG2E_ 1.44269504088896f

typedef __bf16 bf16_t;
typedef __bf16 bf16x2 __attribute__((ext_vector_type(2)));
typedef __bf16 bf16x4 __attribute__((ext_vector_type(4)));
typedef __bf16 bf16x8 __attribute__((ext_vector_type(8)));
typedef float f32x4 __attribute__((ext_vector_type(4)));
typedef float f32x16 __attribute__((ext_vector_type(16)));

// attn LDS: double-buffered K (64x128 @256B rows) + V^T (128x64 @128B rows), 32KB per buffer
#define KSB(p, r, cb) ((p) * 32768 + (r) * 256 + ((cb) ^ (((r) & 7) << 4)))
#define VSB(p, r, cb) ((p) * 32768 + 16384 + (r) * 128 + ((cb) ^ (((r) & 7) << 4)))

#define NW_ 4194304L   // E*E
#define NX_ 8388608L   // M*E

// ---------------- fused fp32 -> bf16 convert of all 7 inputs ----------------
__global__ void cvt_all_k(const float* __restrict__ xq, const float* __restrict__ xkv,
                          const float* __restrict__ bias,
                          const float* __restrict__ wq, const float* __restrict__ wk,
                          const float* __restrict__ wv, const float* __restrict__ wo,
                          bf16_t* __restrict__ ws) {
    const long NW4 = NW_ / 4, NX4 = NX_ / 4;
    long i4 = (long)blockIdx.x * 256 + threadIdx.x;
    const float* src; long off; float scale = 1.0f;
    if (i4 < 4 * NW4) {
        long r = i4 / NW4;
        src = (r == 0) ? wq : (r == 1) ? wk : (r == 2) ? wv : wo;
        off = i4 - r * NW4;
    } else if (i4 < 5 * NW4) {
        src = bias; off = i4 - 4 * NW4; scale = LOG2E_;
    } else if (i4 < 5 * NW4 + NX4) {
        src = xq; off = i4 - 5 * NW4;
    } else {
        src = xkv; off = i4 - 5 * NW4 - NX4;
    }
    float4 v = ((const float4*)src)[off];
    bf16x4 o = { (bf16_t)(v.x * scale), (bf16_t)(v.y * scale),
                 (bf16_t)(v.z * scale), (bf16_t)(v.w * scale) };
    ((bf16x4*)ws)[i4] = o;
}

// ---------------- mixed-tile 8-wave 4-phase NT GEMM (counted-vmcnt pipeline) ----------------
template<typename OutT, int GROUPS, int FULLB>
__global__ __launch_bounds__(512, 2) void gemm_mix(
    const bf16_t* __restrict__ A0g, const bf16_t* __restrict__ A1g,
    const bf16_t* __restrict__ W0, OutT* __restrict__ C0) {
    __shared__ __align__(16) unsigned char smem[131072];
    const int tid = threadIdx.x;
    const int wid = tid >> 6, lane = tid & 63;
    const int fr = lane & 15, fq = lane >> 4;
    const int wm = wid >> 2, wn = wid & 3;        // 2M x 4N wave grid
    int slot, hsel, isfull;
    {
        int bid = blockIdx.x;
        if (FULLB > 0 && bid < FULLB) {
            slot = (bid & 7) * (FULLB >> 3) + (bid >> 3);
            hsel = 0; isfull = 1;
        } else {
            const int n = (int)gridDim.x - FULLB;
            int sub = bid - FULLB;
            int s = (sub & 7) * (n >> 3) + (sub >> 3);
            slot = FULLB + (s >> 1); hsel = s & 1; isfull = 0;
        }
    }
    const int g = slot >> 7;
    const int r0 = slot & 127;
    const int bm = r0 >> 3, bn = r0 & 7;
    const long arow0 = (long)bm * 256 + (long)hsel * 128;
    const long brow0 = (long)bn * 256;
    const bf16_t* Ab = ((GROUPS > 1 && g > 0) ? A1g : A0g) + arow0 * E_;
    const bf16_t* Wb = W0 + (long)g * (long)E_ * E_ + brow0 * E_;
    const int srow = tid >> 2;
    const int sc16 = tid & 3;

    auto STG = [&](const bf16_t* base, unsigned matOff, int h, unsigned bufb, int kt) {
        #pragma unroll
        for (int kk = 0; kk < 2; ++kk) {
            int col = kk * 32 + ((sc16 ^ ((srow >> 1) & 3)) * 8);
            __builtin_amdgcn_global_load_lds(
                (const __attribute__((address_space(1))) void*)(base + (long)(h * 128 + srow) * E_ + kt + col),
                (__attribute__((address_space(3))) void*)(smem + bufb + matOff + h * 16384u + kk * 8192u + tid * 16), 16, 0, 0);
        }
    };
    auto LDA = [&](unsigned pb, int kk, int r) -> bf16x8 {
        int lr = r & 127;
        return *(const bf16x8*)(smem + pb + (unsigned)(r >> 7) * 16384u + kk * 8192u + lr * 64 + ((fq ^ ((lr >> 1) & 3)) << 4));
    };
    auto LDB = [&](unsigned pb, int kk, int ni) -> bf16x8 {
        int r = wn * 64 + ni * 16 + fr;
        int lr = r & 127;
        return *(const bf16x8*)(smem + pb + 32768u + (unsigned)(r >> 7) * 16384u + kk * 8192u + lr * 64 + ((fq ^ ((lr >> 1) & 3)) << 4));
    };

    if (FULLB > 0 && isfull) {
        f32x4 acc[8][4] = {};
        STG(Ab, 0u,     0, 0u, 0); STG(Ab, 0u,     1, 0u, 0);
        STG(Wb, 32768u, 0, 0u, 0); STG(Wb, 32768u, 1, 0u, 0);
        STG(Wb, 32768u, 0, 65536u, 64); STG(Wb, 32768u, 1, 65536u, 64);
        asm volatile("s_waitcnt vmcnt(4)" ::: "memory");
        __builtin_amdgcn_s_barrier();
        bf16x8 bq[2][4];
        #pragma unroll 2
        for (int t = 0; t < 32; ++t) {
            const unsigned pb = (unsigned)(t & 1) * 65536u;
            const unsigned sbA = 65536u - pb;
            const int ktA = ((t + 1) & 31) * 64;
            const int ktB = ((t + 2) & 31) * 64;
            bf16x8 a[2][2];
            #pragma unroll
            for (int kk = 0; kk < 2; ++kk) {
                a[kk][0] = LDA(pb, kk, wm * 128 + 0 * 16 + fr);
                a[kk][1] = LDA(pb, kk, wm * 128 + 1 * 16 + fr);
                #pragma unroll
                for (int ni = 0; ni < 4; ++ni) bq[kk][ni] = LDB(pb, kk, ni);
            }
            STG(Ab, 0u, 0, sbA, ktA);
            __builtin_amdgcn_s_barrier();
            asm volatile("s_waitcnt lgkmcnt(0)" ::: "memory");
            __builtin_amdgcn_sched_barrier(0);
            __builtin_amdgcn_s_setprio(1);
            #pragma unroll
            for (int kk = 0; kk < 2; ++kk)
                #pragma unroll
                for (int ni = 0; ni < 4; ++ni) {
                    acc[0][ni] = __builtin_amdgcn_mfma_f32_16x16x32_bf16(a[kk][0], bq[kk][ni], acc[0][ni], 0, 0, 0);
                    acc[1][ni] = __builtin_amdgcn_mfma_f32_16x16x32_bf16(a[kk][1], bq[kk][ni], acc[1][ni], 0, 0, 0);
                }
            __builtin_amdgcn_s_setprio(0);
            __builtin_amdgcn_s_barrier();
            #pragma unroll
            for (int kk = 0; kk < 2; ++kk) {
                a[kk][0] = LDA(pb, kk, wm * 128 + 2 * 16 + fr);
                a[kk][1] = LDA(pb, kk, wm * 128 + 3 * 16 + fr);
            }
            STG(Ab, 0u, 1, sbA, ktA);
            __builtin_amdgcn_s_barrier();
            asm volatile("s_waitcnt lgkmcnt(0)" ::: "memory");
            __builtin_amdgcn_sched_barrier(0);
            __builtin_amdgcn_s_setprio(1);
            #pragma unroll
            for (int kk = 0; kk < 2; ++kk)
                #pragma unroll
                for (int ni = 0; ni < 4; ++ni) {
                    acc[2][ni] = __builtin_amdgcn_mfma_f32_16x16x32_bf16(a[kk][0], bq[kk][ni], acc[2][ni], 0, 0, 0);
                    acc[3][ni] = __builtin_amdgcn_mfma_f32_16x16x32_bf16(a[kk][1], bq[kk][ni], acc[3][ni], 0, 0, 0);
                }
            __builtin_amdgcn_s_setprio(0);
            __builtin_amdgcn_s_barrier();
            #pragma unroll
            for (int kk = 0; kk < 2; ++kk) {
                a[kk][0] = LDA(pb, kk, wm * 128 + 4 * 16 + fr);
                a[kk][1] = LDA(pb, kk, wm * 128 + 5 * 16 + fr);
            }
            STG(Wb, 32768u, 0, pb, ktB);
            __builtin_amdgcn_s_barrier();
            asm volatile("s_waitcnt lgkmcnt(0)" ::: "memory");
            __builtin_amdgcn_sched_barrier(0);
            __builtin_amdgcn_s_setprio(1);
            #pragma unroll
            for (int kk = 0; kk < 2; ++kk)
                #pragma unroll
                for (int ni = 0; ni < 4; ++ni) {
                    acc[4][ni] = __builtin_amdgcn_mfma_f32_16x16x32_bf16(a[kk][0], bq[kk][ni], acc[4][ni], 0, 0, 0);
                    acc[5][ni] = __builtin_amdgcn_mfma_f32_16x16x32_bf16(a[kk][1], bq[kk][ni], acc[5][ni], 0, 0, 0);
                }
            __builtin_amdgcn_s_setprio(0);
            __builtin_amdgcn_s_barrier();
            #pragma unroll
            for (int kk = 0; kk < 2; ++kk) {
                a[kk][0] = LDA(pb, kk, wm * 128 + 6 * 16 + fr);
                a[kk][1] = LDA(pb, kk, wm * 128 + 7 * 16 + fr);
            }
            STG(Wb, 32768u, 1, pb, ktB);
            asm volatile("s_waitcnt vmcnt(4)" ::: "memory");
            __builtin_amdgcn_s_barrier();
            asm volatile("s_waitcnt lgkmcnt(0)" ::: "memory");
            __builtin_amdgcn_sched_barrier(0);
            __builtin_amdgcn_s_setprio(1);
            #pragma unroll
            for (int kk = 0; kk < 2; ++kk)
                #pragma unroll
                for (int ni = 0; ni < 4; ++ni) {
                    acc[6][ni] = __builtin_amdgcn_mfma_f32_16x16x32_bf16(a[kk][0], bq[kk][ni], acc[6][ni], 0, 0, 0);
                    acc[7][ni] = __builtin_amdgcn_mfma_f32_16x16x32_bf16(a[kk][1], bq[kk][ni], acc[7][ni], 0, 0, 0);
                }
            __builtin_amdgcn_s_setprio(0);
            __builtin_amdgcn_s_barrier();
        }
        asm volatile("s_waitcnt vmcnt(0)" ::: "memory");
        OutT* Cg = C0 + (long)g * M_ * E_;
        #pragma unroll
        for (int mi = 0; mi < 8; ++mi)
            #pragma unroll
            for (int i = 0; i < 4; ++i) {
                long row = arow0 + wm * 128 + mi * 16 + fq * 4 + i;
                OutT* crow = Cg + row * E_ + brow0 + wn * 64 + fr;
                #pragma unroll
                for (int ni = 0; ni < 4; ++ni)
                    crow[ni * 16] = (OutT)acc[mi][ni][i];
            }
    } else {
        f32x4 acc[4][4] = {};
        STG(Ab, 0u,     0, 0u, 0);
        STG(Wb, 32768u, 0, 0u, 0); STG(Wb, 32768u, 1, 0u, 0);
        STG(Wb, 32768u, 0, 65536u, 64); STG(Wb, 32768u, 1, 65536u, 64);
        asm volatile("s_waitcnt vmcnt(4)" ::: "memory");
        __builtin_amdgcn_s_barrier();
        bf16x8 bq[2][4];
        #pragma unroll 2
        for (int t = 0; t < 32; ++t) {
            const unsigned pb = (unsigned)(t & 1) * 65536u;
            const unsigned sbA = 65536u - pb;
            const int ktA = ((t + 1) & 31) * 64;
            const int ktB = ((t + 2) & 31) * 64;
            bf16x8 a[2];
            #pragma unroll
            for (int kk = 0; kk < 2; ++kk) {
                a[kk] = LDA(pb, kk, wm * 64 + 0 * 16 + fr);
                #pragma unroll
                for (int ni = 0; ni < 4; ++ni) bq[kk][ni] = LDB(pb, kk, ni);
            }
            STG(Ab, 0u, 0, sbA, ktA);
            __builtin_amdgcn_s_barrier();
            asm volatile("s_waitcnt lgkmcnt(0)" ::: "memory");
            __builtin_amdgcn_sched_barrier(0);
            __builtin_amdgcn_s_setprio(1);
            #pragma unroll
            for (int kk = 0; kk < 2; ++kk)
                #pragma unroll
                for (int ni = 0; ni < 4; ++ni)
                    acc[0][ni] = __builtin_amdgcn_mfma_f32_16x16x32_bf16(a[kk], bq[kk][ni], acc[0][ni], 0, 0, 0);
            __builtin_amdgcn_s_setprio(0);
            __builtin_amdgcn_s_barrier();
            #pragma unroll
            for (int kk = 0; kk < 2; ++kk) a[kk] = LDA(pb, kk, wm * 64 + 1 * 16 + fr);
            __builtin_amdgcn_s_barrier();
            asm volatile("s_waitcnt lgkmcnt(0)" ::: "memory");
            __builtin_amdgcn_sched_barrier(0);
            __builtin_amdgcn_s_setprio(1);
            #pragma unroll
            for (int kk = 0; kk < 2; ++kk)
                #pragma unroll
                for (int ni = 0; ni < 4; ++ni)
                    acc[1][ni] = __builtin_amdgcn_mfma_f32_16x16x32_bf16(a[kk], bq[kk][ni], acc[1][ni], 0, 0, 0);
            __builtin_amdgcn_s_setprio(0);
            __builtin_amdgcn_s_barrier();
            #pragma unroll
            for (int kk = 0; kk < 2; ++kk) a[kk] = LDA(pb, kk, wm * 64 + 2 * 16 + fr);
            STG(Wb, 32768u, 0, pb, ktB);
            __builtin_amdgcn_s_barrier();
            asm volatile("s_waitcnt lgkmcnt(0)" ::: "memory");
            __builtin_amdgcn_sched_barrier(0);
            __builtin_amdgcn_s_setprio(1);
            #pragma unroll
            for (int kk = 0; kk < 2; ++kk)
                #pragma unroll
                for (int ni = 0; ni < 4; ++ni)
                    acc[2][ni] = __builtin_amdgcn_mfma_f32_16x16x32_bf16(a[kk], bq[kk][ni], acc[2][ni], 0, 0, 0);
            __builtin_amdgcn_s_setprio(0);
            __builtin_amdgcn_s_barrier();
            #pragma unroll
            for (int kk = 0; kk < 2; ++kk) a[kk] = LDA(pb, kk, wm * 64 + 3 * 16 + fr);
            STG(Wb, 32768u, 1, pb, ktB);
            asm volatile("s_waitcnt vmcnt(4)" ::: "memory");
            __builtin_amdgcn_s_barrier();
            asm volatile("s_waitcnt lgkmcnt(0)" ::: "memory");
            __builtin_amdgcn_sched_barrier(0);
            __builtin_amdgcn_s_setprio(1);
            #pragma unroll
            for (int kk = 0; kk < 2; ++kk)
                #pragma unroll
                for (int ni = 0; ni < 4; ++ni)
                    acc[3][ni] = __builtin_amdgcn_mfma_f32_16x16x32_bf16(a[kk], bq[kk][ni], acc[3][ni], 0, 0, 0);
            __builtin_amdgcn_s_setprio(0);
            __builtin_amdgcn_s_barrier();
        }
        asm volatile("s_waitcnt vmcnt(0)" ::: "memory");
        OutT* Cg = C0 + (long)g * M_ * E_;
        #pragma unroll
        for (int mi = 0; mi < 4; ++mi)
            #pragma unroll
            for (int i = 0; i < 4; ++i) {
                long row = arow0 + wm * 64 + mi * 16 + fq * 4 + i;
                OutT* crow = Cg + row * E_ + brow0 + wn * 64 + fr;
                #pragma unroll
                for (int ni = 0; ni < 4; ++ni)
                    crow[ni * 16] = (OutT)acc[mi][ni][i];
            }
    }
}

// ---------------- merged: Q/K postprocess (blocks 0..32767) + V transpose (blocks 32768..34815) ----------------
__global__ __launch_bounds__(256) void post_tv_k(
    const bf16_t* __restrict__ Pq, const bf16_t* __restrict__ Pk,
    const bf16_t* __restrict__ Vp,
    const float* __restrict__ qsins, const float* __restrict__ ksins,
    const float* __restrict__ qnscale, const float* __restrict__ knscale,
    bf16_t* __restrict__ outq, bf16_t* __restrict__ outk, bf16_t* __restrict__ Vt) {
    __shared__ bf16_t t[64 * 64];
    if (blockIdx.x < 32768) {
        const int wid = threadIdx.x >> 6, lane = threadIdx.x & 63;
        const int half = blockIdx.x >> 14;
        const long g = (long)(blockIdx.x & 16383) * 4 + wid;
        const bf16_t* P = half ? Pk : Pq;
        const float* sins = half ? ksins : qsins;
        const float* nscale = half ? knscale : qnscale;
        bf16_t* out = half ? outk : outq;
        const int h = (int)(g % H_);
        const long bl = g / H_;
        const int b = (int)(bl / L_), l = (int)(bl % L_);
        bf16x2 xv = *(const bf16x2*)(P + g * D_ + lane * 2);
        float x0 = (float)xv[0], x1 = (float)xv[1];
        float ss = x0 * x0 + x1 * x1;
        #pragma unroll
        for (int m = 1; m < 64; m <<= 1) ss += __shfl_xor(ss, m);
        float r = rsqrtf(ss * (1.0f / 128.0f) + 1e-6f);
        float y0 = x0 * r * nscale[lane * 2];
        float y1 = x1 * r * nscale[lane * 2 + 1];
        float2 cs = *(const float2*)(sins + bl * D_ + lane * 2);
        float z0 = y0 * cs.x - y1 * cs.y;
        float z1 = y1 * cs.x + y0 * cs.y;
        float n2 = z0 * z0 + z1 * z1;
        #pragma unroll
        for (int m = 1; m < 64; m <<= 1) n2 += __shfl_xor(n2, m);
        float inv = 1.0f / fmaxf(sqrtf(n2), 1e-12f);
        bf16x2 o = { (bf16_t)(z0 * inv), (bf16_t)(z1 * inv) };
        *(bf16x2*)(out + (((long)b * H_ + h) * L_ + l) * D_ + lane * 2) = o;
    } else {
        const int idx = blockIdx.x - 32768;
        const int lb = idx & 31;
        const int db = (idx >> 5) & 1;
        const int bh = idx >> 6;
        const int b = bh >> 4, h = bh & 15;
        const bf16_t* src = Vp + ((long)(b * L_ + lb * 64) * H_ + h) * D_ + db * 64;
        #pragma unroll
        for (int it = 0; it < 2; ++it) {
            int i = it * 256 + threadIdx.x;
            int r = i >> 3, c8 = i & 7;
            bf16x8 v = *(const bf16x8*)(src + (long)r * H_ * D_ + c8 * 8);
            *(bf16x8*)&t[r * 64 + (c8 ^ (r >> 3)) * 8] = v;
        }
        __syncthreads();
        bf16_t* dst = Vt + ((long)(b * H_ + h) * D_ + db * 64) * L_ + lb * 64;
        #pragma unroll
        for (int it = 0; it < 2; ++it) {
            int i = it * 256 + threadIdx.x;
            int d = i >> 3, l8 = i & 7;
            bf16x8 o;
            #pragma unroll
            for (int j = 0; j < 8; ++j) {
                int l = l8 * 8 + j;
                o[j] = t[l * 64 + ((d >> 3) ^ l8) * 8 + (d & 7)];
            }
            *(bf16x8*)(dst + (long)d * L_ + l8 * 8) = o;
        }
    }
}

// ---------------- flash attention (32x32 swapped, no-max softmax, 1 barrier/tile,
//                   XCD-locality block swizzle: each XCD owns 4 complete heads) ----------------
__global__ __launch_bounds__(256, 2) void attn_k(
    const bf16_t* __restrict__ Qn, const bf16_t* __restrict__ Kn,
    const bf16_t* __restrict__ Vt, const bf16_t* __restrict__ biasb,
    const float* __restrict__ lsg, bf16_t* __restrict__ AO) {
    __shared__ __align__(16) unsigned char smem[65536];
    const int tid = threadIdx.x;
    const int w = tid >> 6, lane = tid & 63;
    const int lane31 = lane & 31, hi = lane >> 5;
    // XCD-locality swizzle: linear id -> (bh, qb) such that ids = c (mod 8)
    // (one XCD's resident set, 64 blocks) cover bh in [4c,4c+4) x all 16 qb.
    // K/V panels for those 4 heads (~4MB) then live in that XCD's L2.
    int id = blockIdx.y * 16 + blockIdx.x;
    int s = (id & 7) * 64 + (id >> 3);
    const int bh = s >> 4, qb = s & 15;
    const int b = bh >> 4, h = bh & 15;
    const float lsc2 = __expf(fminf(lsg[h], LOGIT_SCALE_MAX_)) * LOG2E_;
    const int qr0 = qb * 128;
    const int qloc = w * 32 + lane31;
    const bf16_t* qrow  = Qn + (((long)b * H_ + h) * L_ + qr0 + qloc) * D_;
    const bf16_t* kbase = Kn + (((long)b * H_ + h) * L_) * D_;
    const bf16_t* vtbase = Vt + ((long)(b * H_ + h) * D_) * L_;
    const bf16_t* brow  = biasb + (long)(qr0 + qloc) * L_;

    const int ksr = tid >> 4, ksc = (tid & 15) * 8;
    const int vsr = tid >> 3, vsc = (tid & 7) * 8;

    bf16x8 qreg[8];
    #pragma unroll
    for (int kk = 0; kk < 8; ++kk)
        qreg[kk] = *(const bf16x8*)(qrow + kk * 16 + 8 * hi);

    f32x16 oacc[4] = {};
    float l_ = 0.f;

    bf16x8 kreg[4], vreg[4];
    #pragma unroll
    for (int it = 0; it < 4; ++it) {
        kreg[it] = *(const bf16x8*)(kbase + (long)(it * 16 + ksr) * D_ + ksc);
        vreg[it] = *(const bf16x8*)(vtbase + (long)(it * 32 + vsr) * L_ + vsc);
    }
    #pragma unroll
    for (int it = 0; it < 4; ++it) {
        *(bf16x8*)(smem + KSB(0, it * 16 + ksr, ksc * 2)) = kreg[it];
        *(bf16x8*)(smem + VSB(0, it * 32 + vsr, vsc * 2)) = vreg[it];
    }
    int p = 0;

    for (int kt = 0; kt < L_; kt += 64) {
        __syncthreads();
        const int ktn = (kt + 64 < L_) ? kt + 64 : 0;
        #pragma unroll
        for (int it = 0; it < 4; ++it) {
            kreg[it] = *(const bf16x8*)(kbase + (long)(ktn + it * 16 + ksr) * D_ + ksc);
            vreg[it] = *(const bf16x8*)(vtbase + (long)(it * 32 + vsr) * L_ + ktn + vsc);
        }
        bf16x4 bb[2][4];
        #pragma unroll
        for (int f = 0; f < 2; ++f)
            #pragma unroll
            for (int rr = 0; rr < 4; ++rr)
                bb[f][rr] = *(const bf16x4*)(brow + kt + f * 32 + rr * 8 + 4 * hi);
        f32x16 sacc[2] = {};
        __builtin_amdgcn_s_setprio(1);
        #pragma unroll
        for (int kk = 0; kk < 8; ++kk) {
            bf16x8 ak0 = *(const bf16x8*)(smem + KSB(p, lane31,      kk * 32 + 16 * hi));
            bf16x8 ak1 = *(const bf16x8*)(smem + KSB(p, 32 + lane31, kk * 32 + 16 * hi));
            sacc[0] = __builtin_amdgcn_mfma_f32_32x32x16_bf16(ak0, qreg[kk], sacc[0], 0, 0, 0);
            sacc[1] = __builtin_amdgcn_mfma_f32_32x32x16_bf16(ak1, qreg[kk], sacc[1], 0, 0, 0);
        }
        __builtin_amdgcn_s_setprio(0);
        float ps = 0.f;
        unsigned int wv[2][4][2];
        #pragma unroll
        for (int f = 0; f < 2; ++f)
            #pragma unroll
            for (int rr = 0; rr < 4; ++rr)
                #pragma unroll
                for (int wi = 0; wi < 2; ++wi) {
                    float pa = __builtin_amdgcn_exp2f(sacc[f][rr * 4 + wi * 2]     * lsc2 + (float)bb[f][rr][wi * 2]);
                    float pc = __builtin_amdgcn_exp2f(sacc[f][rr * 4 + wi * 2 + 1] * lsc2 + (float)bb[f][rr][wi * 2 + 1]);
                    ps += pa + pc;
                    bf16x2 t = { (bf16_t)pa, (bf16_t)pc };
                    wv[f][rr][wi] = __builtin_bit_cast(unsigned int, t);
                }
        ps += __shfl_xor(ps, 32);
        l_ += ps;
        bf16x8 pb_[4];
        #pragma unroll
        for (int kk = 0; kk < 4; ++kk) {
            const int f = kk >> 1;
            const int a2 = (kk & 1) * 2;
            unsigned int A0 = wv[f][a2][0],     A1 = wv[f][a2][1];
            unsigned int B0 = wv[f][a2 + 1][0], B1 = wv[f][a2 + 1][1];
            unsigned int own0  = hi ? B0 : A0;
            unsigned int own1  = hi ? B1 : A1;
            unsigned int send0 = hi ? A0 : B0;
            unsigned int send1 = hi ? A1 : B1;
            unsigned int recv0 = __shfl_xor(send0, 32);
            unsigned int recv1 = __shfl_xor(send1, 32);
            uint4 uu;
            uu.x = hi ? recv0 : own0;
            uu.y = hi ? recv1 : own1;
            uu.z = hi ? own0  : recv0;
            uu.w = hi ? own1  : recv1;
            pb_[kk] = __builtin_bit_cast(bf16x8, uu);
        }
        __builtin_amdgcn_s_setprio(1);
        #pragma unroll
        for (int df = 0; df < 4; ++df)
            #pragma unroll
            for (int kk = 0; kk < 4; ++kk) {
                bf16x8 av = *(const bf16x8*)(smem + VSB(p, df * 32 + lane31, kk * 32 + 16 * hi));
                oacc[df] = __builtin_amdgcn_mfma_f32_32x32x16_bf16(av, pb_[kk], oacc[df], 0, 0, 0);
            }
        __builtin_amdgcn_s_setprio(0);
        if (kt + 64 < L_) {
            #pragma unroll
            for (int it = 0; it < 4; ++it) {
                *(bf16x8*)(smem + KSB(p ^ 1, it * 16 + ksr, ksc * 2)) = kreg[it];
                *(bf16x8*)(smem + VSB(p ^ 1, it * 32 + vsr, vsc * 2)) = vreg[it];
            }
        }
        p ^= 1;
    }
    __syncthreads();
    float inv = 1.0f / l_;
    #pragma unroll
    for (int df = 0; df < 4; ++df)
        #pragma unroll
        for (int rg = 0; rg < 16; ++rg) {
            int d = df * 32 + (rg & 3) + 8 * (rg >> 2) + 4 * hi;
            *(bf16_t*)(smem + qloc * 264 + d * 2) = (bf16_t)(oacc[df][rg] * inv);
        }
    __syncthreads();
    #pragma unroll
    for (int it = 0; it < 8; ++it) {
        int idx = it * 256 + tid;
        int row = idx >> 4, c = idx & 15;
        bf16x8 v = *(const bf16x8*)(smem + row * 264 + c * 16);
        *(bf16x8*)(AO + ((long)b * L_ + qr0 + row) * E_ + h * D_ + c * 8) = v;
    }
}

extern "C" void kernel_launch(void* const* d_in, const int* in_sizes, int n_in,
                              void* d_out, int out_size, void* d_ws, size_t ws_size,
                              hipStream_t stream) {
    const float* inputs_q  = (const float*)d_in[0];
    const float* inputs_kv = (const float*)d_in[1];
    const float* bias      = (const float*)d_in[2];
    const float* q_sin     = (const float*)d_in[3];
    const float* k_sin     = (const float*)d_in[4];
    const float* Wq        = (const float*)d_in[5];
    const float* Wk        = (const float*)d_in[6];
    const float* Wv        = (const float*)d_in[7];
    const float* Wo        = (const float*)d_in[8];
    const float* qns       = (const float*)d_in[9];
    const float* kns       = (const float*)d_in[10];
    const float* lsg       = (const float*)d_in[11];

    bf16_t* ws = (bf16_t*)d_ws;
    const long NW = NW_;
    const long NX = NX_;
    bf16_t* Wq_b   = ws;                    // Wq,Wk,Wv contiguous
    bf16_t* Wo_b   = ws + 3 * NW;
    bf16_t* bias_b = ws + 4 * NW;
    bf16_t* Xq     = bias_b + NW;
    bf16_t* Xkv    = Xq + NX;
    bf16_t* Qp     = Xkv + NX;              // Qp,Kp,Vp contiguous for grouped GEMM
    bf16_t* Kp     = Qp + NX;
    bf16_t* Vp     = Kp + NX;
    bf16_t* Qn = Xq;    // alias (Xq dead after GEMM Q)
    bf16_t* Kn = Xkv;   // alias (Xkv dead after GEMMs)
    bf16_t* AO = Qp;    // alias (Qp dead after postproc Q)
    bf16_t* Vtr = Kp;   // alias (Kp dead after postproc K)
    if (ws_size < (size_t)(5 * NW + 5 * NX) * 2) return;

    {
        long n4 = (5 * NW + 2 * NX) / 4;
        cvt_all_k<<<dim3((unsigned)(n4 / 256)), dim3(256), 0, stream>>>(
            inputs_q, inputs_kv, bias, Wq, Wk, Wv, Wo, ws);
    }

    // QKV projection: 256 full 256x256 blocks (Q,K) + 256 half 128x256 blocks (V) = 2 clean rounds
    gemm_mix<bf16_t, 3, 256><<<dim3(512), dim3(512), 0, stream>>>(Xq, Xkv, Wq_b, Qp);

    post_tv_k<<<dim3(34816), dim3(256), 0, stream>>>(
        Qp, Kp, Vp, q_sin, k_sin, qns, kns, Qn, Kn, Vtr);

    attn_k<<<dim3(L_ / 128, B_ * H_), dim3(256), 0, stream>>>(Qn, Kn, Vtr, bias_b, lsg, AO);

    // O projection: 256 half 128x256 blocks = 1 clean round
    gemm_mix<float, 1, 0><<<dim3(256), dim3(512), 0, stream>>>(AO, AO, Wo_b, (float*)d_out);
}

// Round 18
// 306.076 us; speedup vs baseline: 1.2023x; 1.0100x over previous
//
#include <hip/hip_runtime.h>
#include <hip/hip_bf16.h>

#define B_ 2
#define L_ 2048
#define E_ 2048
#define H_ 16
#define D_ 128
#define M_ (B_*L_)
#define LOGIT_SCALE_MAX_ 4.6051701859880914f
#define LOG2E_ 1.44269504088896f

typedef __bf16 bf16_t;
typedef __bf16 bf16x2 __attribute__((ext_vector_type(2)));
typedef __bf16 bf16x4 __attribute__((ext_vector_type(4)));
typedef __bf16 bf16x8 __attribute__((ext_vector_type(8)));
typedef float f32x4 __attribute__((ext_vector_type(4)));
typedef float f32x16 __attribute__((ext_vector_type(16)));

// attn LDS, double-buffered, widened swizzles (reads 2-way = free):
// K tile 64x128 @256B rows: XOR slot bits with (r&7) AND bit3 from (r>>3)&1 -> 16-slot spread.
// V^T tile 128x64: paired into 256B LDS rows (ldsrow=r>>1, half=r&1), XOR (ldsrow&7).
#define KSB(p, r, cb) ((p) * 32768 + (r) * 256 + ((cb) ^ (((r) & 7) << 4) ^ ((((r) >> 3) & 1) << 7)))
#define VSB(p, r, cb) ((p) * 32768 + 16384 + (((r) >> 1) * 256) + (((r) & 1) * 128) + ((cb) ^ ((((r) >> 1) & 7) << 4)))

#define NW_ 4194304L   // E*E
#define NX_ 8388608L   // M*E

// ---------------- fused fp32 -> bf16 convert of all 7 inputs ----------------
__global__ void cvt_all_k(const float* __restrict__ xq, const float* __restrict__ xkv,
                          const float* __restrict__ bias,
                          const float* __restrict__ wq, const float* __restrict__ wk,
                          const float* __restrict__ wv, const float* __restrict__ wo,
                          bf16_t* __restrict__ ws) {
    const long NW4 = NW_ / 4, NX4 = NX_ / 4;
    long i4 = (long)blockIdx.x * 256 + threadIdx.x;
    const float* src; long off; float scale = 1.0f;
    if (i4 < 4 * NW4) {
        long r = i4 / NW4;
        src = (r == 0) ? wq : (r == 1) ? wk : (r == 2) ? wv : wo;
        off = i4 - r * NW4;
    } else if (i4 < 5 * NW4) {
        src = bias; off = i4 - 4 * NW4; scale = LOG2E_;
    } else if (i4 < 5 * NW4 + NX4) {
        src = xq; off = i4 - 5 * NW4;
    } else {
        src = xkv; off = i4 - 5 * NW4 - NX4;
    }
    float4 v = ((const float4*)src)[off];
    bf16x4 o = { (bf16_t)(v.x * scale), (bf16_t)(v.y * scale),
                 (bf16_t)(v.z * scale), (bf16_t)(v.w * scale) };
    ((bf16x4*)ws)[i4] = o;
}

// ---------------- mixed-tile 8-wave 4-phase NT GEMM (counted-vmcnt pipeline) ----------------
template<typename OutT, int GROUPS, int FULLB>
__global__ __launch_bounds__(512, 2) void gemm_mix(
    const bf16_t* __restrict__ A0g, const bf16_t* __restrict__ A1g,
    const bf16_t* __restrict__ W0, OutT* __restrict__ C0) {
    __shared__ __align__(16) unsigned char smem[131072];
    const int tid = threadIdx.x;
    const int wid = tid >> 6, lane = tid & 63;
    const int fr = lane & 15, fq = lane >> 4;
    const int wm = wid >> 2, wn = wid & 3;        // 2M x 4N wave grid
    int slot, hsel, isfull;
    {
        int bid = blockIdx.x;
        if (FULLB > 0 && bid < FULLB) {
            slot = (bid & 7) * (FULLB >> 3) + (bid >> 3);
            hsel = 0; isfull = 1;
        } else {
            const int n = (int)gridDim.x - FULLB;
            int sub = bid - FULLB;
            int s = (sub & 7) * (n >> 3) + (sub >> 3);
            slot = FULLB + (s >> 1); hsel = s & 1; isfull = 0;
        }
    }
    const int g = slot >> 7;
    const int r0 = slot & 127;
    const int bm = r0 >> 3, bn = r0 & 7;
    const long arow0 = (long)bm * 256 + (long)hsel * 128;
    const long brow0 = (long)bn * 256;
    const bf16_t* Ab = ((GROUPS > 1 && g > 0) ? A1g : A0g) + arow0 * E_;
    const bf16_t* Wb = W0 + (long)g * (long)E_ * E_ + brow0 * E_;
    const int srow = tid >> 2;
    const int sc16 = tid & 3;

    auto STG = [&](const bf16_t* base, unsigned matOff, int h, unsigned bufb, int kt) {
        #pragma unroll
        for (int kk = 0; kk < 2; ++kk) {
            int col = kk * 32 + ((sc16 ^ ((srow >> 1) & 3)) * 8);
            __builtin_amdgcn_global_load_lds(
                (const __attribute__((address_space(1))) void*)(base + (long)(h * 128 + srow) * E_ + kt + col),
                (__attribute__((address_space(3))) void*)(smem + bufb + matOff + h * 16384u + kk * 8192u + tid * 16), 16, 0, 0);
        }
    };
    auto LDA = [&](unsigned pb, int kk, int r) -> bf16x8 {
        int lr = r & 127;
        return *(const bf16x8*)(smem + pb + (unsigned)(r >> 7) * 16384u + kk * 8192u + lr * 64 + ((fq ^ ((lr >> 1) & 3)) << 4));
    };
    auto LDB = [&](unsigned pb, int kk, int ni) -> bf16x8 {
        int r = wn * 64 + ni * 16 + fr;
        int lr = r & 127;
        return *(const bf16x8*)(smem + pb + 32768u + (unsigned)(r >> 7) * 16384u + kk * 8192u + lr * 64 + ((fq ^ ((lr >> 1) & 3)) << 4));
    };

    if (FULLB > 0 && isfull) {
        f32x4 acc[8][4] = {};
        STG(Ab, 0u,     0, 0u, 0); STG(Ab, 0u,     1, 0u, 0);
        STG(Wb, 32768u, 0, 0u, 0); STG(Wb, 32768u, 1, 0u, 0);
        STG(Wb, 32768u, 0, 65536u, 64); STG(Wb, 32768u, 1, 65536u, 64);
        asm volatile("s_waitcnt vmcnt(4)" ::: "memory");
        __builtin_amdgcn_s_barrier();
        bf16x8 bq[2][4];
        #pragma unroll 2
        for (int t = 0; t < 32; ++t) {
            const unsigned pb = (unsigned)(t & 1) * 65536u;
            const unsigned sbA = 65536u - pb;
            const int ktA = ((t + 1) & 31) * 64;
            const int ktB = ((t + 2) & 31) * 64;
            bf16x8 a[2][2];
            #pragma unroll
            for (int kk = 0; kk < 2; ++kk) {
                a[kk][0] = LDA(pb, kk, wm * 128 + 0 * 16 + fr);
                a[kk][1] = LDA(pb, kk, wm * 128 + 1 * 16 + fr);
                #pragma unroll
                for (int ni = 0; ni < 4; ++ni) bq[kk][ni] = LDB(pb, kk, ni);
            }
            STG(Ab, 0u, 0, sbA, ktA);
            __builtin_amdgcn_s_barrier();
            asm volatile("s_waitcnt lgkmcnt(0)" ::: "memory");
            __builtin_amdgcn_sched_barrier(0);
            __builtin_amdgcn_s_setprio(1);
            #pragma unroll
            for (int kk = 0; kk < 2; ++kk)
                #pragma unroll
                for (int ni = 0; ni < 4; ++ni) {
                    acc[0][ni] = __builtin_amdgcn_mfma_f32_16x16x32_bf16(a[kk][0], bq[kk][ni], acc[0][ni], 0, 0, 0);
                    acc[1][ni] = __builtin_amdgcn_mfma_f32_16x16x32_bf16(a[kk][1], bq[kk][ni], acc[1][ni], 0, 0, 0);
                }
            __builtin_amdgcn_s_setprio(0);
            __builtin_amdgcn_s_barrier();
            #pragma unroll
            for (int kk = 0; kk < 2; ++kk) {
                a[kk][0] = LDA(pb, kk, wm * 128 + 2 * 16 + fr);
                a[kk][1] = LDA(pb, kk, wm * 128 + 3 * 16 + fr);
            }
            STG(Ab, 0u, 1, sbA, ktA);
            __builtin_amdgcn_s_barrier();
            asm volatile("s_waitcnt lgkmcnt(0)" ::: "memory");
            __builtin_amdgcn_sched_barrier(0);
            __builtin_amdgcn_s_setprio(1);
            #pragma unroll
            for (int kk = 0; kk < 2; ++kk)
                #pragma unroll
                for (int ni = 0; ni < 4; ++ni) {
                    acc[2][ni] = __builtin_amdgcn_mfma_f32_16x16x32_bf16(a[kk][0], bq[kk][ni], acc[2][ni], 0, 0, 0);
                    acc[3][ni] = __builtin_amdgcn_mfma_f32_16x16x32_bf16(a[kk][1], bq[kk][ni], acc[3][ni], 0, 0, 0);
                }
            __builtin_amdgcn_s_setprio(0);
            __builtin_amdgcn_s_barrier();
            #pragma unroll
            for (int kk = 0; kk < 2; ++kk) {
                a[kk][0] = LDA(pb, kk, wm * 128 + 4 * 16 + fr);
                a[kk][1] = LDA(pb, kk, wm * 128 + 5 * 16 + fr);
            }
            STG(Wb, 32768u, 0, pb, ktB);
            __builtin_amdgcn_s_barrier();
            asm volatile("s_waitcnt lgkmcnt(0)" ::: "memory");
            __builtin_amdgcn_sched_barrier(0);
            __builtin_amdgcn_s_setprio(1);
            #pragma unroll
            for (int kk = 0; kk < 2; ++kk)
                #pragma unroll
                for (int ni = 0; ni < 4; ++ni) {
                    acc[4][ni] = __builtin_amdgcn_mfma_f32_16x16x32_bf16(a[kk][0], bq[kk][ni], acc[4][ni], 0, 0, 0);
                    acc[5][ni] = __builtin_amdgcn_mfma_f32_16x16x32_bf16(a[kk][1], bq[kk][ni], acc[5][ni], 0, 0, 0);
                }
            __builtin_amdgcn_s_setprio(0);
            __builtin_amdgcn_s_barrier();
            #pragma unroll
            for (int kk = 0; kk < 2; ++kk) {
                a[kk][0] = LDA(pb, kk, wm * 128 + 6 * 16 + fr);
                a[kk][1] = LDA(pb, kk, wm * 128 + 7 * 16 + fr);
            }
            STG(Wb, 32768u, 1, pb, ktB);
            asm volatile("s_waitcnt vmcnt(4)" ::: "memory");
            __builtin_amdgcn_s_barrier();
            asm volatile("s_waitcnt lgkmcnt(0)" ::: "memory");
            __builtin_amdgcn_sched_barrier(0);
            __builtin_amdgcn_s_setprio(1);
            #pragma unroll
            for (int kk = 0; kk < 2; ++kk)
                #pragma unroll
                for (int ni = 0; ni < 4; ++ni) {
                    acc[6][ni] = __builtin_amdgcn_mfma_f32_16x16x32_bf16(a[kk][0], bq[kk][ni], acc[6][ni], 0, 0, 0);
                    acc[7][ni] = __builtin_amdgcn_mfma_f32_16x16x32_bf16(a[kk][1], bq[kk][ni], acc[7][ni], 0, 0, 0);
                }
            __builtin_amdgcn_s_setprio(0);
            __builtin_amdgcn_s_barrier();
        }
        asm volatile("s_waitcnt vmcnt(0)" ::: "memory");
        OutT* Cg = C0 + (long)g * M_ * E_;
        #pragma unroll
        for (int mi = 0; mi < 8; ++mi)
            #pragma unroll
            for (int i = 0; i < 4; ++i) {
                long row = arow0 + wm * 128 + mi * 16 + fq * 4 + i;
                OutT* crow = Cg + row * E_ + brow0 + wn * 64 + fr;
                #pragma unroll
                for (int ni = 0; ni < 4; ++ni)
                    crow[ni * 16] = (OutT)acc[mi][ni][i];
            }
    } else {
        f32x4 acc[4][4] = {};
        STG(Ab, 0u,     0, 0u, 0);
        STG(Wb, 32768u, 0, 0u, 0); STG(Wb, 32768u, 1, 0u, 0);
        STG(Wb, 32768u, 0, 65536u, 64); STG(Wb, 32768u, 1, 65536u, 64);
        asm volatile("s_waitcnt vmcnt(4)" ::: "memory");
        __builtin_amdgcn_s_barrier();
        bf16x8 bq[2][4];
        #pragma unroll 2
        for (int t = 0; t < 32; ++t) {
            const unsigned pb = (unsigned)(t & 1) * 65536u;
            const unsigned sbA = 65536u - pb;
            const int ktA = ((t + 1) & 31) * 64;
            const int ktB = ((t + 2) & 31) * 64;
            bf16x8 a[2];
            #pragma unroll
            for (int kk = 0; kk < 2; ++kk) {
                a[kk] = LDA(pb, kk, wm * 64 + 0 * 16 + fr);
                #pragma unroll
                for (int ni = 0; ni < 4; ++ni) bq[kk][ni] = LDB(pb, kk, ni);
            }
            STG(Ab, 0u, 0, sbA, ktA);
            __builtin_amdgcn_s_barrier();
            asm volatile("s_waitcnt lgkmcnt(0)" ::: "memory");
            __builtin_amdgcn_sched_barrier(0);
            __builtin_amdgcn_s_setprio(1);
            #pragma unroll
            for (int kk = 0; kk < 2; ++kk)
                #pragma unroll
                for (int ni = 0; ni < 4; ++ni)
                    acc[0][ni] = __builtin_amdgcn_mfma_f32_16x16x32_bf16(a[kk], bq[kk][ni], acc[0][ni], 0, 0, 0);
            __builtin_amdgcn_s_setprio(0);
            __builtin_amdgcn_s_barrier();
            #pragma unroll
            for (int kk = 0; kk < 2; ++kk) a[kk] = LDA(pb, kk, wm * 64 + 1 * 16 + fr);
            __builtin_amdgcn_s_barrier();
            asm volatile("s_waitcnt lgkmcnt(0)" ::: "memory");
            __builtin_amdgcn_sched_barrier(0);
            __builtin_amdgcn_s_setprio(1);
            #pragma unroll
            for (int kk = 0; kk < 2; ++kk)
                #pragma unroll
                for (int ni = 0; ni < 4; ++ni)
                    acc[1][ni] = __builtin_amdgcn_mfma_f32_16x16x32_bf16(a[kk], bq[kk][ni], acc[1][ni], 0, 0, 0);
            __builtin_amdgcn_s_setprio(0);
            __builtin_amdgcn_s_barrier();
            #pragma unroll
            for (int kk = 0; kk < 2; ++kk) a[kk] = LDA(pb, kk, wm * 64 + 2 * 16 + fr);
            STG(Wb, 32768u, 0, pb, ktB);
            __builtin_amdgcn_s_barrier();
            asm volatile("s_waitcnt lgkmcnt(0)" ::: "memory");
            __builtin_amdgcn_sched_barrier(0);
            __builtin_amdgcn_s_setprio(1);
            #pragma unroll
            for (int kk = 0; kk < 2; ++kk)
                #pragma unroll
                for (int ni = 0; ni < 4; ++ni)
                    acc[2][ni] = __builtin_amdgcn_mfma_f32_16x16x32_bf16(a[kk], bq[kk][ni], acc[2][ni], 0, 0, 0);
            __builtin_amdgcn_s_setprio(0);
            __builtin_amdgcn_s_barrier();
            #pragma unroll
            for (int kk = 0; kk < 2; ++kk) a[kk] = LDA(pb, kk, wm * 64 + 3 * 16 + fr);
            STG(Wb, 32768u, 1, pb, ktB);
            asm volatile("s_waitcnt vmcnt(4)" ::: "memory");
            __builtin_amdgcn_s_barrier();
            asm volatile("s_waitcnt lgkmcnt(0)" ::: "memory");
            __builtin_amdgcn_sched_barrier(0);
            __builtin_amdgcn_s_setprio(1);
            #pragma unroll
            for (int kk = 0; kk < 2; ++kk)
                #pragma unroll
                for (int ni = 0; ni < 4; ++ni)
                    acc[3][ni] = __builtin_amdgcn_mfma_f32_16x16x32_bf16(a[kk], bq[kk][ni], acc[3][ni], 0, 0, 0);
            __builtin_amdgcn_s_setprio(0);
            __builtin_amdgcn_s_barrier();
        }
        asm volatile("s_waitcnt vmcnt(0)" ::: "memory");
        OutT* Cg = C0 + (long)g * M_ * E_;
        #pragma unroll
        for (int mi = 0; mi < 4; ++mi)
            #pragma unroll
            for (int i = 0; i < 4; ++i) {
                long row = arow0 + wm * 64 + mi * 16 + fq * 4 + i;
                OutT* crow = Cg + row * E_ + brow0 + wn * 64 + fr;
                #pragma unroll
                for (int ni = 0; ni < 4; ++ni)
                    crow[ni * 16] = (OutT)acc[mi][ni][i];
            }
    }
}

// ---------------- merged: Q/K postprocess (blocks 0..32767) + V transpose (blocks 32768..34815) ----------------
__global__ __launch_bounds__(256) void post_tv_k(
    const bf16_t* __restrict__ Pq, const bf16_t* __restrict__ Pk,
    const bf16_t* __restrict__ Vp,
    const float* __restrict__ qsins, const float* __restrict__ ksins,
    const float* __restrict__ qnscale, const float* __restrict__ knscale,
    bf16_t* __restrict__ outq, bf16_t* __restrict__ outk, bf16_t* __restrict__ Vt) {
    __shared__ bf16_t t[64 * 64];
    if (blockIdx.x < 32768) {
        const int wid = threadIdx.x >> 6, lane = threadIdx.x & 63;
        const int half = blockIdx.x >> 14;
        const long g = (long)(blockIdx.x & 16383) * 4 + wid;
        const bf16_t* P = half ? Pk : Pq;
        const float* sins = half ? ksins : qsins;
        const float* nscale = half ? knscale : qnscale;
        bf16_t* out = half ? outk : outq;
        const int h = (int)(g % H_);
        const long bl = g / H_;
        const int b = (int)(bl / L_), l = (int)(bl % L_);
        bf16x2 xv = *(const bf16x2*)(P + g * D_ + lane * 2);
        float x0 = (float)xv[0], x1 = (float)xv[1];
        float ss = x0 * x0 + x1 * x1;
        #pragma unroll
        for (int m = 1; m < 64; m <<= 1) ss += __shfl_xor(ss, m);
        float r = rsqrtf(ss * (1.0f / 128.0f) + 1e-6f);
        float y0 = x0 * r * nscale[lane * 2];
        float y1 = x1 * r * nscale[lane * 2 + 1];
        float2 cs = *(const float2*)(sins + bl * D_ + lane * 2);
        float z0 = y0 * cs.x - y1 * cs.y;
        float z1 = y1 * cs.x + y0 * cs.y;
        float n2 = z0 * z0 + z1 * z1;
        #pragma unroll
        for (int m = 1; m < 64; m <<= 1) n2 += __shfl_xor(n2, m);
        float inv = 1.0f / fmaxf(sqrtf(n2), 1e-12f);
        bf16x2 o = { (bf16_t)(z0 * inv), (bf16_t)(z1 * inv) };
        *(bf16x2*)(out + (((long)b * H_ + h) * L_ + l) * D_ + lane * 2) = o;
    } else {
        const int idx = blockIdx.x - 32768;
        const int lb = idx & 31;
        const int db = (idx >> 5) & 1;
        const int bh = idx >> 6;
        const int b = bh >> 4, h = bh & 15;
        const bf16_t* src = Vp + ((long)(b * L_ + lb * 64) * H_ + h) * D_ + db * 64;
        #pragma unroll
        for (int it = 0; it < 2; ++it) {
            int i = it * 256 + threadIdx.x;
            int r = i >> 3, c8 = i & 7;
            bf16x8 v = *(const bf16x8*)(src + (long)r * H_ * D_ + c8 * 8);
            *(bf16x8*)&t[r * 64 + (c8 ^ (r >> 3)) * 8] = v;
        }
        __syncthreads();
        bf16_t* dst = Vt + ((long)(b * H_ + h) * D_ + db * 64) * L_ + lb * 64;
        #pragma unroll
        for (int it = 0; it < 2; ++it) {
            int i = it * 256 + threadIdx.x;
            int d = i >> 3, l8 = i & 7;
            bf16x8 o;
            #pragma unroll
            for (int j = 0; j < 8; ++j) {
                int l = l8 * 8 + j;
                o[j] = t[l * 64 + ((d >> 3) ^ l8) * 8 + (d & 7)];
            }
            *(bf16x8*)(dst + (long)d * L_ + l8 * 8) = o;
        }
    }
}

// ---------------- flash attention (32x32 swapped, no-max softmax, 1 barrier/tile,
//                   XCD-locality block swizzle, widened LDS swizzles) ----------------
__global__ __launch_bounds__(256, 2) void attn_k(
    const bf16_t* __restrict__ Qn, const bf16_t* __restrict__ Kn,
    const bf16_t* __restrict__ Vt, const bf16_t* __restrict__ biasb,
    const float* __restrict__ lsg, bf16_t* __restrict__ AO) {
    __shared__ __align__(16) unsigned char smem[65536];
    const int tid = threadIdx.x;
    const int w = tid >> 6, lane = tid & 63;
    const int lane31 = lane & 31, hi = lane >> 5;
    int id = blockIdx.y * 16 + blockIdx.x;
    int s = (id & 7) * 64 + (id >> 3);
    const int bh = s >> 4, qb = s & 15;
    const int b = bh >> 4, h = bh & 15;
    const float lsc2 = __expf(fminf(lsg[h], LOGIT_SCALE_MAX_)) * LOG2E_;
    const int qr0 = qb * 128;
    const int qloc = w * 32 + lane31;
    const bf16_t* qrow  = Qn + (((long)b * H_ + h) * L_ + qr0 + qloc) * D_;
    const bf16_t* kbase = Kn + (((long)b * H_ + h) * L_) * D_;
    const bf16_t* vtbase = Vt + ((long)(b * H_ + h) * D_) * L_;
    const bf16_t* brow  = biasb + (long)(qr0 + qloc) * L_;

    const int ksr = tid >> 4, ksc = (tid & 15) * 8;
    const int vsr = tid >> 3, vsc = (tid & 7) * 8;

    bf16x8 qreg[8];
    #pragma unroll
    for (int kk = 0; kk < 8; ++kk)
        qreg[kk] = *(const bf16x8*)(qrow + kk * 16 + 8 * hi);

    f32x16 oacc[4] = {};
    float l_ = 0.f;

    bf16x8 kreg[4], vreg[4];
    #pragma unroll
    for (int it = 0; it < 4; ++it) {
        kreg[it] = *(const bf16x8*)(kbase + (long)(it * 16 + ksr) * D_ + ksc);
        vreg[it] = *(const bf16x8*)(vtbase + (long)(it * 32 + vsr) * L_ + vsc);
    }
    #pragma unroll
    for (int it = 0; it < 4; ++it) {
        *(bf16x8*)(smem + KSB(0, it * 16 + ksr, ksc * 2)) = kreg[it];
        *(bf16x8*)(smem + VSB(0, it * 32 + vsr, vsc * 2)) = vreg[it];
    }
    int p = 0;

    for (int kt = 0; kt < L_; kt += 64) {
        __syncthreads();
        const int ktn = (kt + 64 < L_) ? kt + 64 : 0;
        #pragma unroll
        for (int it = 0; it < 4; ++it) {
            kreg[it] = *(const bf16x8*)(kbase + (long)(ktn + it * 16 + ksr) * D_ + ksc);
            vreg[it] = *(const bf16x8*)(vtbase + (long)(it * 32 + vsr) * L_ + ktn + vsc);
        }
        bf16x4 bb[2][4];
        #pragma unroll
        for (int f = 0; f < 2; ++f)
            #pragma unroll
            for (int rr = 0; rr < 4; ++rr)
                bb[f][rr] = *(const bf16x4*)(brow + kt + f * 32 + rr * 8 + 4 * hi);
        f32x16 sacc[2] = {};
        __builtin_amdgcn_s_setprio(1);
        #pragma unroll
        for (int kk = 0; kk < 8; ++kk) {
            bf16x8 ak0 = *(const bf16x8*)(smem + KSB(p, lane31,      kk * 32 + 16 * hi));
            bf16x8 ak1 = *(const bf16x8*)(smem + KSB(p, 32 + lane31, kk * 32 + 16 * hi));
            sacc[0] = __builtin_amdgcn_mfma_f32_32x32x16_bf16(ak0, qreg[kk], sacc[0], 0, 0, 0);
            sacc[1] = __builtin_amdgcn_mfma_f32_32x32x16_bf16(ak1, qreg[kk], sacc[1], 0, 0, 0);
        }
        __builtin_amdgcn_s_setprio(0);
        float ps = 0.f;
        unsigned int wv[2][4][2];
        #pragma unroll
        for (int f = 0; f < 2; ++f)
            #pragma unroll
            for (int rr = 0; rr < 4; ++rr)
                #pragma unroll
                for (int wi = 0; wi < 2; ++wi) {
                    float pa = __builtin_amdgcn_exp2f(sacc[f][rr * 4 + wi * 2]     * lsc2 + (float)bb[f][rr][wi * 2]);
                    float pc = __builtin_amdgcn_exp2f(sacc[f][rr * 4 + wi * 2 + 1] * lsc2 + (float)bb[f][rr][wi * 2 + 1]);
                    ps += pa + pc;
                    bf16x2 t = { (bf16_t)pa, (bf16_t)pc };
                    wv[f][rr][wi] = __builtin_bit_cast(unsigned int, t);
                }
        ps += __shfl_xor(ps, 32);
        l_ += ps;
        bf16x8 pb_[4];
        #pragma unroll
        for (int kk = 0; kk < 4; ++kk) {
            const int f = kk >> 1;
            const int a2 = (kk & 1) * 2;
            unsigned int A0 = wv[f][a2][0],     A1 = wv[f][a2][1];
            unsigned int B0 = wv[f][a2 + 1][0], B1 = wv[f][a2 + 1][1];
            unsigned int own0  = hi ? B0 : A0;
            unsigned int own1  = hi ? B1 : A1;
            unsigned int send0 = hi ? A0 : B0;
            unsigned int send1 = hi ? A1 : B1;
            unsigned int recv0 = __shfl_xor(send0, 32);
            unsigned int recv1 = __shfl_xor(send1, 32);
            uint4 uu;
            uu.x = hi ? recv0 : own0;
            uu.y = hi ? recv1 : own1;
            uu.z = hi ? own0  : recv0;
            uu.w = hi ? own1  : recv1;
            pb_[kk] = __builtin_bit_cast(bf16x8, uu);
        }
        __builtin_amdgcn_s_setprio(1);
        #pragma unroll
        for (int df = 0; df < 4; ++df)
            #pragma unroll
            for (int kk = 0; kk < 4; ++kk) {
                bf16x8 av = *(const bf16x8*)(smem + VSB(p, df * 32 + lane31, kk * 32 + 16 * hi));
                oacc[df] = __builtin_amdgcn_mfma_f32_32x32x16_bf16(av, pb_[kk], oacc[df], 0, 0, 0);
            }
        __builtin_amdgcn_s_setprio(0);
        if (kt + 64 < L_) {
            #pragma unroll
            for (int it = 0; it < 4; ++it) {
                *(bf16x8*)(smem + KSB(p ^ 1, it * 16 + ksr, ksc * 2)) = kreg[it];
                *(bf16x8*)(smem + VSB(p ^ 1, it * 32 + vsr, vsc * 2)) = vreg[it];
            }
        }
        p ^= 1;
    }
    __syncthreads();
    float inv = 1.0f / l_;
    #pragma unroll
    for (int df = 0; df < 4; ++df)
        #pragma unroll
        for (int rg = 0; rg < 16; ++rg) {
            int d = df * 32 + (rg & 3) + 8 * (rg >> 2) + 4 * hi;
            *(bf16_t*)(smem + qloc * 264 + d * 2) = (bf16_t)(oacc[df][rg] * inv);
        }
    __syncthreads();
    #pragma unroll
    for (int it = 0; it < 8; ++it) {
        int idx = it * 256 + tid;
        int row = idx >> 4, c = idx & 15;
        bf16x8 v = *(const bf16x8*)(smem + row * 264 + c * 16);
        *(bf16x8*)(AO + ((long)b * L_ + qr0 + row) * E_ + h * D_ + c * 8) = v;
    }
}

extern "C" void kernel_launch(void* const* d_in, const int* in_sizes, int n_in,
                              void* d_out, int out_size, void* d_ws, size_t ws_size,
                              hipStream_t stream) {
    const float* inputs_q  = (const float*)d_in[0];
    const float* inputs_kv = (const float*)d_in[1];
    const float* bias      = (const float*)d_in[2];
    const float* q_sin     = (const float*)d_in[3];
    const float* k_sin     = (const float*)d_in[4];
    const float* Wq        = (const float*)d_in[5];
    const float* Wk        = (const float*)d_in[6];
    const float* Wv        = (const float*)d_in[7];
    const float* Wo        = (const float*)d_in[8];
    const float* qns       = (const float*)d_in[9];
    const float* kns       = (const float*)d_in[10];
    const float* lsg       = (const float*)d_in[11];

    bf16_t* ws = (bf16_t*)d_ws;
    const long NW = NW_;
    const long NX = NX_;
    bf16_t* Wq_b   = ws;                    // Wq,Wk,Wv contiguous
    bf16_t* Wo_b   = ws + 3 * NW;
    bf16_t* bias_b = ws + 4 * NW;
    bf16_t* Xq     = bias_b + NW;
    bf16_t* Xkv    = Xq + NX;
    bf16_t* Qp     = Xkv + NX;              // Qp,Kp,Vp contiguous for grouped GEMM
    bf16_t* Kp     = Qp + NX;
    bf16_t* Vp     = Kp + NX;
    bf16_t* Qn = Xq;    // alias (Xq dead after GEMM Q)
    bf16_t* Kn = Xkv;   // alias (Xkv dead after GEMMs)
    bf16_t* AO = Qp;    // alias (Qp dead after postproc Q)
    bf16_t* Vtr = Kp;   // alias (Kp dead after postproc K)
    if (ws_size < (size_t)(5 * NW + 5 * NX) * 2) return;

    {
        long n4 = (5 * NW + 2 * NX) / 4;
        cvt_all_k<<<dim3((unsigned)(n4 / 256)), dim3(256), 0, stream>>>(
            inputs_q, inputs_kv, bias, Wq, Wk, Wv, Wo, ws);
    }

    // QKV projection: 256 full 256x256 blocks (Q,K) + 256 half 128x256 blocks (V) = 2 clean rounds
    gemm_mix<bf16_t, 3, 256><<<dim3(512), dim3(512), 0, stream>>>(Xq, Xkv, Wq_b, Qp);

    post_tv_k<<<dim3(34816), dim3(256), 0, stream>>>(
        Qp, Kp, Vp, q_sin, k_sin, qns, kns, Qn, Kn, Vtr);

    attn_k<<<dim3(L_ / 128, B_ * H_), dim3(256), 0, stream>>>(Qn, Kn, Vtr, bias_b, lsg, AO);

    // O projection: 256 half 128x256 blocks = 1 clean round
    gemm_mix<float, 1, 0><<<dim3(256), dim3(512), 0, stream>>>(AO, AO, Wo_b, (float*)d_out);
}